// Round 3
// baseline (3183.325 us; speedup 1.0000x reference)
//
#include <hip/hip_runtime.h>
#include <math.h>

#define NN 100000
#define EE 400000
#define RR 3
#define HH 4
#define DD 32
#define FH 128   // H*D
#define OUTF 64

__device__ __forceinline__ void atomicMaxF(float* addr, float val) {
    // works for all finite floats incl. -inf init
    if (val >= 0.f) atomicMax((int*)addr, __float_as_int(val));
    else            atomicMin((unsigned int*)addr, __float_as_uint(val));
}

__global__ __launch_bounds__(256) void zero_k(float4* __restrict__ p, int n4)
{
    int i = blockIdx.x * 256 + threadIdx.x;
    if (i < n4) p[i] = make_float4(0.f, 0.f, 0.f, 0.f);
}

// C[M x ldc block] = A[M x 128] @ B[128 x (64-col tile)] (+bias)
// BM=128, BN=64, full K=128. LDS: Bs 32KB + As 16.5KB -> 3 blocks/CU.
__global__ __launch_bounds__(256) void gemm_k128(
    const float* __restrict__ A, const float* __restrict__ B,
    const float* __restrict__ bias, float* __restrict__ C,
    int M, int ldb, int ldc)
{
    __shared__ float Bs[128 * 64];
    __shared__ float As[32 * 129];
    const int t = threadIdx.x;
    const int col0 = blockIdx.y * 64;

    // load B tile [128 x 64] (coalesced float4, conflict-free writes)
    for (int j = t; j < 2048; j += 256) {
        int k = j >> 4, c4 = (j & 15) << 2;
        *(float4*)&Bs[k * 64 + c4] = *(const float4*)&B[(size_t)k * ldb + col0 + c4];
    }

    const int row0 = blockIdx.x * 128;
    const int c0 = (t & 15) << 2;   // 4 cols
    const int r0 = (t >> 4) << 3;   // 8 rows
    float acc[8][4] = {};

    for (int kb = 0; kb < 4; ++kb) {
        __syncthreads();
        // stage A tile [128 rows x 32 k], transposed into As[k][row] (pad 129)
        #pragma unroll
        for (int i = 0; i < 4; ++i) {
            int j = t + i * 256;
            int row = j >> 3, k4 = (j & 7) << 2;
            int grow = row0 + row;
            float4 v = make_float4(0.f, 0.f, 0.f, 0.f);
            if (grow < M) v = *(const float4*)&A[(size_t)grow * 128 + kb * 32 + k4];
            As[(k4 + 0) * 129 + row] = v.x;
            As[(k4 + 1) * 129 + row] = v.y;
            As[(k4 + 2) * 129 + row] = v.z;
            As[(k4 + 3) * 129 + row] = v.w;
        }
        __syncthreads();
        #pragma unroll
        for (int k = 0; k < 32; ++k) {
            float4 a0 = *(float4*)&As[k * 129 + r0];
            float4 a1 = *(float4*)&As[k * 129 + r0 + 4];
            float4 b  = *(float4*)&Bs[(kb * 32 + k) * 64 + c0];
            float av[8] = {a0.x, a0.y, a0.z, a0.w, a1.x, a1.y, a1.z, a1.w};
            float bv[4] = {b.x, b.y, b.z, b.w};
            #pragma unroll
            for (int i = 0; i < 8; ++i)
                #pragma unroll
                for (int jj = 0; jj < 4; ++jj)
                    acc[i][jj] += av[i] * bv[jj];
        }
    }

    float4 bv = make_float4(0.f, 0.f, 0.f, 0.f);
    if (bias) bv = *(const float4*)&bias[col0 + c0];
    #pragma unroll
    for (int i = 0; i < 8; ++i) {
        int grow = row0 + r0 + i;
        if (grow < M) {
            float4 o;
            o.x = acc[i][0] + bv.x; o.y = acc[i][1] + bv.y;
            o.z = acc[i][2] + bv.z; o.w = acc[i][3] + bv.w;
            *(float4*)&C[(size_t)grow * ldc + col0 + c0] = o;
        }
    }
}

// per (node, head): el/er dot products + init m=-inf, s=0
__global__ __launch_bounds__(256) void elr_init(
    const float* __restrict__ z, const float* __restrict__ al, const float* __restrict__ ar,
    float* __restrict__ el, float* __restrict__ er,
    float* __restrict__ m, float* __restrict__ s)
{
    int i = blockIdx.x * 256 + threadIdx.x;
    if (i >= NN * HH) return;
    int h = i & 3;
    const float* zp  = z + (size_t)(i >> 2) * FH + h * DD;
    const float* alp = al + h * DD;
    const float* arp = ar + h * DD;
    float ea = 0.f, eb = 0.f;
    #pragma unroll
    for (int d = 0; d < DD; d += 4) {
        float4 zv = *(const float4*)&zp[d];
        float4 av = *(const float4*)&alp[d];
        float4 rv = *(const float4*)&arp[d];
        ea += zv.x * av.x + zv.y * av.y + zv.z * av.z + zv.w * av.w;
        eb += zv.x * rv.x + zv.y * rv.y + zv.z * rv.z + zv.w * rv.w;
    }
    el[i] = ea; er[i] = eb;
    m[i] = -INFINITY; s[i] = 0.f;
}

__global__ __launch_bounds__(256) void edge_score(
    const int* __restrict__ src, const int* __restrict__ dst,
    const float* __restrict__ el, const float* __restrict__ er,
    float* __restrict__ e_out, float* __restrict__ m)
{
    int i = blockIdx.x * 256 + threadIdx.x;
    if (i >= EE * HH) return;
    int eid = i >> 2, h = i & 3;
    int sN = src[eid], dN = dst[eid];
    float v = el[sN * HH + h] + er[dN * HH + h];
    v = v > 0.f ? v : 0.2f * v;   // GAT leaky_relu
    e_out[i] = v;
    atomicMaxF(&m[dN * HH + h], v);
}

__global__ __launch_bounds__(256) void edge_expk(
    const int* __restrict__ dst, float* e_inout,
    const float* __restrict__ m, float* __restrict__ ssum)
{
    int i = blockIdx.x * 256 + threadIdx.x;
    if (i >= EE * HH) return;
    int eid = i >> 2, h = i & 3;
    int dN = dst[eid];
    float v = expf(e_inout[i] - m[dN * HH + h]);
    e_inout[i] = v;
    atomicAdd(&ssum[dN * HH + h], v);
}

__global__ __launch_bounds__(256) void inv_k(const float* __restrict__ s, float* __restrict__ invs)
{
    int i = blockIdx.x * 256 + threadIdx.x;
    if (i >= NN * HH) return;
    invs[i] = 1.0f / s[i];
}

// one thread per (edge, feature)
__global__ __launch_bounds__(256) void edge_msg(
    const int* __restrict__ src, const int* __restrict__ dst,
    const float* __restrict__ z, const float* __restrict__ ex,
    const float* __restrict__ invs, float* __restrict__ acc)
{
    int i = blockIdx.x * 256 + threadIdx.x;
    if (i >= EE * FH) return;
    int eid = i >> 7, f = i & 127, h = f >> 5;
    int sN = src[eid], dN = dst[eid];
    float alpha = ex[eid * HH + h] * invs[dN * HH + h];
    atomicAdd(&acc[(size_t)dN * FH + f], z[(size_t)sN * FH + f] * alpha);
}

// h_out = act((acc + sum_r b[r]) / R)
__global__ __launch_bounds__(256) void finalize_k(
    const float* __restrict__ acc, const float* __restrict__ b,
    float* __restrict__ out, int act)
{
    int i = blockIdx.x * 256 + threadIdx.x;
    if (i >= NN * FH) return;
    int f = i & 127;
    float bs = b[f] + b[FH + f] + b[2 * FH + f];
    float v = (acc[i] + bs) * (1.f / 3.f);
    if (act) v = v > 0.f ? v : 0.01f * v;
    out[i] = v;
}

extern "C" void kernel_launch(void* const* d_in, const int* in_sizes, int n_in,
                              void* d_out, int out_size, void* d_ws, size_t ws_size,
                              hipStream_t stream)
{
    const float* x    = (const float*)d_in[0];
    const int*   src  = (const int*)d_in[1];
    const int*   dst  = (const int*)d_in[2];
    const float* W0   = (const float*)d_in[3];
    const float* al0  = (const float*)d_in[4];
    const float* ar0  = (const float*)d_in[5];
    const float* b0   = (const float*)d_in[6];
    const float* W12  = (const float*)d_in[7];
    const float* al12 = (const float*)d_in[8];
    const float* ar12 = (const float*)d_in[9];
    const float* b12  = (const float*)d_in[10];
    const float* Wlin = (const float*)d_in[11];
    const float* blin = (const float*)d_in[12];
    float* out = (float*)d_out;

    char* ws = (char*)d_ws;
    size_t off = 0;
    auto alloc = [&](size_t bytes) {
        void* p = ws + off;
        off += (bytes + 255) & ~(size_t)255;
        return p;
    };
    float* bufX = (float*)alloc((size_t)NN * FH * 4);  // acc
    float* bufY = (float*)alloc((size_t)NN * FH * 4);  // z / h ping
    float* bufZ = (float*)alloc((size_t)NN * FH * 4);  // z / h pong
    float* el   = (float*)alloc((size_t)NN * HH * 4);
    float* er   = (float*)alloc((size_t)NN * HH * 4);
    float* mbuf = (float*)alloc((size_t)NN * HH * 4);
    float* sbuf = (float*)alloc((size_t)NN * HH * 4);
    float* invs = (float*)alloc((size_t)NN * HH * 4);
    float* ebuf = (float*)alloc((size_t)EE * HH * 4);

    const int GEMM_GX = (NN + 127) / 128;        // 782
    const dim3 gemm_grid(GEMM_GX, 2);
    const int g_nh  = (NN * HH + 255) / 256;     // 1563
    const int g_eh  = (EE * HH + 255) / 256;     // 6250
    const int g_ef  = (EE * FH) / 256;           // 200000
    const int g_nf  = (NN * FH) / 256;           // 50000
    const int g_z4  = (NN * FH / 4 + 255) / 256; // 12500

    for (int lay = 0; lay < 3; ++lay) {
        const float* Wl = (lay == 0) ? W0  : W12  + (size_t)(lay - 1) * RR * 128 * 128;
        const float* aL = (lay == 0) ? al0 : al12 + (size_t)(lay - 1) * RR * FH;
        const float* aR = (lay == 0) ? ar0 : ar12 + (size_t)(lay - 1) * RR * FH;
        const float* bL = (lay == 0) ? b0  : b12  + (size_t)(lay - 1) * RR * FH;

        const float* hin = (lay == 0) ? x : ((lay == 1) ? bufY : bufZ);
        float* accb = bufX;
        float* zb   = (lay == 1) ? bufZ : bufY;
        float* hout = zb;  // z is dead by finalize time

        zero_k<<<g_z4, 256, 0, stream>>>((float4*)accb, NN * FH / 4);

        for (int r = 0; r < RR; ++r) {
            const float* Wr  = Wl + (size_t)r * 128 * 128;
            const float* alr = aL + (size_t)r * FH;
            const float* arr = aR + (size_t)r * FH;
            const int* src_r = src + (size_t)r * EE;
            const int* dst_r = dst + (size_t)r * EE;

            gemm_k128<<<gemm_grid, 256, 0, stream>>>(hin, Wr, nullptr, zb, NN, 128, 128);
            elr_init<<<g_nh, 256, 0, stream>>>(zb, alr, arr, el, er, mbuf, sbuf);
            edge_score<<<g_eh, 256, 0, stream>>>(src_r, dst_r, el, er, ebuf, mbuf);
            edge_expk<<<g_eh, 256, 0, stream>>>(dst_r, ebuf, mbuf, sbuf);
            inv_k<<<g_nh, 256, 0, stream>>>(sbuf, invs);
            edge_msg<<<g_ef, 256, 0, stream>>>(src_r, dst_r, zb, ebuf, invs, accb);
        }
        finalize_k<<<g_nf, 256, 0, stream>>>(accb, bL, hout, (lay < 2) ? 1 : 0);
    }

    // final linear: [N x 128] @ [128 x 64] + blin
    gemm_k128<<<dim3(GEMM_GX, 1), 256, 0, stream>>>(bufY, Wlin, blin, out, NN, 64, 64);
}

// Round 4
// 1847.417 us; speedup vs baseline: 1.7231x; 1.7231x over previous
//
#include <hip/hip_runtime.h>
#include <math.h>

#define NN 100000
#define EE 400000
#define RR 3
#define HH 4
#define DD 32
#define FH 128   // H*D
#define OUTF 64

#define SN (RR * NN)          // scanned elements (per-relation degree arrays concatenated)
#define SB 1024               // elems per scan block
#define SNB ((SN + SB - 1) / SB)  // 293

// ---------------- CSR build ----------------

__global__ __launch_bounds__(256) void zero_i(int* __restrict__ p, int n)
{
    int i = blockIdx.x * 256 + threadIdx.x;
    if (i < n) p[i] = 0;
}

__global__ __launch_bounds__(256) void count_k(const int* __restrict__ dst, int* __restrict__ deg)
{
    int i = blockIdx.x * 256 + threadIdx.x;
    if (i >= RR * EE) return;
    int r = i / EE;
    atomicAdd(&deg[r * NN + dst[i]], 1);
}

__global__ __launch_bounds__(256) void scan_s1(const int* __restrict__ in, int* __restrict__ part)
{
    __shared__ int lds[256];
    int b = blockIdx.x, t = threadIdx.x;
    int base = b * SB + t * 4;
    int s = 0;
    #pragma unroll
    for (int k = 0; k < 4; ++k) { int idx = base + k; if (idx < SN) s += in[idx]; }
    lds[t] = s; __syncthreads();
    for (int off = 128; off > 0; off >>= 1) {
        if (t < off) lds[t] += lds[t + off];
        __syncthreads();
    }
    if (t == 0) part[b] = lds[0];
}

__global__ __launch_bounds__(512) void scan_s2(int* __restrict__ part)
{
    __shared__ int lds[512];
    int t = threadIdx.x;
    lds[t] = (t < SNB) ? part[t] : 0;
    __syncthreads();
    for (int off = 1; off < 512; off <<= 1) {
        int add = (t >= off) ? lds[t - off] : 0;
        __syncthreads();
        lds[t] += add;
        __syncthreads();
    }
    if (t < SNB) part[t] = (t == 0) ? 0 : lds[t - 1];
}

__global__ __launch_bounds__(256) void scan_s3(const int* __restrict__ in, const int* __restrict__ part,
                                               int* __restrict__ out)
{
    __shared__ int lds[256];
    int b = blockIdx.x, t = threadIdx.x;
    int base = b * SB + t * 4;
    int v[4]; int s = 0;
    #pragma unroll
    for (int k = 0; k < 4; ++k) {
        v[k] = (base + k < SN) ? in[base + k] : 0;
        s += v[k];
    }
    lds[t] = s; __syncthreads();
    for (int off = 1; off < 256; off <<= 1) {
        int add = (t >= off) ? lds[t - off] : 0;
        __syncthreads();
        lds[t] += add;
        __syncthreads();
    }
    int run = part[b] + ((t == 0) ? 0 : lds[t - 1]);
    #pragma unroll
    for (int k = 0; k < 4; ++k) {
        if (base + k < SN) out[base + k] = run;
        run += v[k];
    }
    if (b == 0 && t == 0) out[SN] = RR * EE;
}

__global__ __launch_bounds__(256) void copy_i(const int* __restrict__ a, int* __restrict__ b, int n)
{
    int i = blockIdx.x * 256 + threadIdx.x;
    if (i < n) b[i] = a[i];
}

__global__ __launch_bounds__(256) void scatter_k(const int* __restrict__ src, const int* __restrict__ dst,
                                                 int* __restrict__ cursor, int* __restrict__ col)
{
    int i = blockIdx.x * 256 + threadIdx.x;
    if (i >= RR * EE) return;
    int r = i / EE;
    int slot = atomicAdd(&cursor[r * NN + dst[i]], 1);
    col[slot] = src[i];
}

// ---------------- dense GEMM (fp32 vector ALU) ----------------
// C[M x ldc block] = A[M x 128] @ B[128 x (64-col tile)] (+bias)
__global__ __launch_bounds__(256) void gemm_k128(
    const float* __restrict__ A, const float* __restrict__ B,
    const float* __restrict__ bias, float* __restrict__ C,
    int M, int ldb, int ldc)
{
    __shared__ float Bs[128 * 64];
    __shared__ float As[32 * 129];
    const int t = threadIdx.x;
    const int col0 = blockIdx.y * 64;

    for (int j = t; j < 2048; j += 256) {
        int k = j >> 4, c4 = (j & 15) << 2;
        *(float4*)&Bs[k * 64 + c4] = *(const float4*)&B[(size_t)k * ldb + col0 + c4];
    }

    const int row0 = blockIdx.x * 128;
    const int c0 = (t & 15) << 2;
    const int r0 = (t >> 4) << 3;
    float acc[8][4] = {};

    for (int kb = 0; kb < 4; ++kb) {
        __syncthreads();
        #pragma unroll
        for (int i = 0; i < 4; ++i) {
            int j = t + i * 256;
            int row = j >> 3, k4 = (j & 7) << 2;
            int grow = row0 + row;
            float4 v = make_float4(0.f, 0.f, 0.f, 0.f);
            if (grow < M) v = *(const float4*)&A[(size_t)grow * 128 + kb * 32 + k4];
            As[(k4 + 0) * 129 + row] = v.x;
            As[(k4 + 1) * 129 + row] = v.y;
            As[(k4 + 2) * 129 + row] = v.z;
            As[(k4 + 3) * 129 + row] = v.w;
        }
        __syncthreads();
        #pragma unroll
        for (int k = 0; k < 32; ++k) {
            float4 a0 = *(float4*)&As[k * 129 + r0];
            float4 a1 = *(float4*)&As[k * 129 + r0 + 4];
            float4 b  = *(float4*)&Bs[(kb * 32 + k) * 64 + c0];
            float av[8] = {a0.x, a0.y, a0.z, a0.w, a1.x, a1.y, a1.z, a1.w};
            float bv[4] = {b.x, b.y, b.z, b.w};
            #pragma unroll
            for (int i = 0; i < 8; ++i)
                #pragma unroll
                for (int jj = 0; jj < 4; ++jj)
                    acc[i][jj] += av[i] * bv[jj];
        }
    }

    float4 bv = make_float4(0.f, 0.f, 0.f, 0.f);
    if (bias) bv = *(const float4*)&bias[col0 + c0];
    #pragma unroll
    for (int i = 0; i < 8; ++i) {
        int grow = row0 + r0 + i;
        if (grow < M) {
            float4 o;
            o.x = acc[i][0] + bv.x; o.y = acc[i][1] + bv.y;
            o.z = acc[i][2] + bv.z; o.w = acc[i][3] + bv.w;
            *(float4*)&C[(size_t)grow * ldc + col0 + c0] = o;
        }
    }
}

// per (node, head): el/er dot products
__global__ __launch_bounds__(256) void elr_init(
    const float* __restrict__ z, const float* __restrict__ al, const float* __restrict__ ar,
    float* __restrict__ el, float* __restrict__ er)
{
    int i = blockIdx.x * 256 + threadIdx.x;
    if (i >= NN * HH) return;
    int h = i & 3;
    const float* zp  = z + (size_t)(i >> 2) * FH + h * DD;
    const float* alp = al + h * DD;
    const float* arp = ar + h * DD;
    float ea = 0.f, eb = 0.f;
    #pragma unroll
    for (int d = 0; d < DD; d += 4) {
        float4 zv = *(const float4*)&zp[d];
        float4 av = *(const float4*)&alp[d];
        float4 rv = *(const float4*)&arp[d];
        ea += zv.x * av.x + zv.y * av.y + zv.z * av.z + zv.w * av.w;
        eb += zv.x * rv.x + zv.y * rv.y + zv.z * rv.z + zv.w * rv.w;
    }
    el[i] = ea; er[i] = eb;
}

// fused per-dst softmax + aggregation. One wave per dst node, no atomics.
// rowptr: global CSR offsets for this relation (length N+1 view); col: global src array.
__global__ __launch_bounds__(256) void gat_agg(
    const int* __restrict__ rowptr, const int* __restrict__ col,
    const float* __restrict__ z,
    const float* __restrict__ el, const float* __restrict__ er,
    float* __restrict__ acc, int add_flag)
{
    int wave = (blockIdx.x * 256 + threadIdx.x) >> 6;
    int lane = threadIdx.x & 63;
    if (wave >= NN) return;
    const int d = wave;
    const int p0 = rowptr[d], p1 = rowptr[d + 1];
    const int deg = p1 - p0;

    // ---- phase A: online softmax stats (16 edges x 4 heads per chunk) ----
    const int h = lane & 3;
    const float erd = er[d * HH + h];
    float m = -INFINITY, ssum = 0.f;
    for (int base = 0; base < deg; base += 16) {
        int e = base + (lane >> 2);
        float v = -INFINITY;
        if (e < deg) {
            int s = col[p0 + e];
            v = el[s * HH + h] + erd;
            v = v > 0.f ? v : 0.2f * v;
        }
        float cm = v;
        cm = fmaxf(cm, __shfl_xor(cm, 4));
        cm = fmaxf(cm, __shfl_xor(cm, 8));
        cm = fmaxf(cm, __shfl_xor(cm, 16));
        cm = fmaxf(cm, __shfl_xor(cm, 32));
        float mnew = fmaxf(m, cm);
        float ex = (e < deg) ? __expf(v - mnew) : 0.f;
        ex += __shfl_xor(ex, 4);
        ex += __shfl_xor(ex, 8);
        ex += __shfl_xor(ex, 16);
        ex += __shfl_xor(ex, 32);
        ssum = ssum * __expf(m - mnew) + ex;
        m = mnew;
    }
    float inv = (ssum > 0.f) ? 1.f / ssum : 0.f;

    // ---- phase B: aggregate alpha * z[src] ; lane covers feats 2*lane, 2*lane+1 ----
    const int hp = lane >> 4;              // head of this lane's features
    const float mh   = __shfl(m, hp);
    const float invh = __shfl(inv, hp);
    const float erh  = __shfl(erd, hp);
    float2 a = make_float2(0.f, 0.f);
    for (int e = 0; e < deg; ++e) {
        int s = col[p0 + e];
        float v = el[s * HH + hp] + erh;
        v = v > 0.f ? v : 0.2f * v;
        float alpha = __expf(v - mh) * invh;
        float2 zr = *(const float2*)&z[(size_t)s * FH + lane * 2];
        a.x += alpha * zr.x;
        a.y += alpha * zr.y;
    }
    float2* outp = (float2*)&acc[(size_t)d * FH + lane * 2];
    if (add_flag) { float2 o = *outp; a.x += o.x; a.y += o.y; }
    *outp = a;
}

// h_out = act((acc + sum_r b[r]) / R)
__global__ __launch_bounds__(256) void finalize_k(
    const float* __restrict__ acc, const float* __restrict__ b,
    float* __restrict__ out, int act)
{
    int i = blockIdx.x * 256 + threadIdx.x;
    if (i >= NN * FH) return;
    int f = i & 127;
    float bs = b[f] + b[FH + f] + b[2 * FH + f];
    float v = (acc[i] + bs) * (1.f / 3.f);
    if (act) v = v > 0.f ? v : 0.01f * v;
    out[i] = v;
}

extern "C" void kernel_launch(void* const* d_in, const int* in_sizes, int n_in,
                              void* d_out, int out_size, void* d_ws, size_t ws_size,
                              hipStream_t stream)
{
    const float* x    = (const float*)d_in[0];
    const int*   src  = (const int*)d_in[1];
    const int*   dst  = (const int*)d_in[2];
    const float* W0   = (const float*)d_in[3];
    const float* al0  = (const float*)d_in[4];
    const float* ar0  = (const float*)d_in[5];
    const float* b0   = (const float*)d_in[6];
    const float* W12  = (const float*)d_in[7];
    const float* al12 = (const float*)d_in[8];
    const float* ar12 = (const float*)d_in[9];
    const float* b12  = (const float*)d_in[10];
    const float* Wlin = (const float*)d_in[11];
    const float* blin = (const float*)d_in[12];
    float* out = (float*)d_out;

    char* ws = (char*)d_ws;
    size_t off = 0;
    auto alloc = [&](size_t bytes) {
        void* p = ws + off;
        off += (bytes + 255) & ~(size_t)255;
        return p;
    };
    float* bufX = (float*)alloc((size_t)NN * FH * 4);  // acc
    float* bufY = (float*)alloc((size_t)NN * FH * 4);  // z / h ping
    float* bufZ = (float*)alloc((size_t)NN * FH * 4);  // z / h pong
    float* el   = (float*)alloc((size_t)NN * HH * 4);
    float* er   = (float*)alloc((size_t)NN * HH * 4);
    int* rowptr = (int*)alloc((size_t)(SN + 1) * 4);
    int* cursor = (int*)alloc((size_t)SN * 4);
    int* colarr = (int*)alloc((size_t)RR * EE * 4);
    int* part   = (int*)alloc((size_t)SNB * 4);

    const int GEMM_GX = (NN + 127) / 128;         // 782
    const dim3 gemm_grid(GEMM_GX, 2);
    const int g_nh  = (NN * HH + 255) / 256;      // 1563
    const int g_nf  = (NN * FH) / 256;            // 50000
    const int g_3e  = (RR * EE + 255) / 256;      // 4688
    const int g_3n  = (SN + 255) / 256;           // 1172
    const int g_agg = NN / 4;                     // 25000 (4 waves/block, 1 dst/wave)

    // ---- build CSR once (same graph for all layers) ----
    zero_i<<<g_3n, 256, 0, stream>>>(cursor, SN);
    count_k<<<g_3e, 256, 0, stream>>>(dst, cursor);
    scan_s1<<<SNB, 256, 0, stream>>>(cursor, part);
    scan_s2<<<1, 512, 0, stream>>>(part);
    scan_s3<<<SNB, 256, 0, stream>>>(cursor, part, rowptr);
    copy_i<<<g_3n, 256, 0, stream>>>(rowptr, cursor, SN);
    scatter_k<<<g_3e, 256, 0, stream>>>(src, dst, cursor, colarr);

    for (int lay = 0; lay < 3; ++lay) {
        const float* Wl = (lay == 0) ? W0  : W12  + (size_t)(lay - 1) * RR * 128 * 128;
        const float* aL = (lay == 0) ? al0 : al12 + (size_t)(lay - 1) * RR * FH;
        const float* aR = (lay == 0) ? ar0 : ar12 + (size_t)(lay - 1) * RR * FH;
        const float* bL = (lay == 0) ? b0  : b12  + (size_t)(lay - 1) * RR * FH;

        const float* hin = (lay == 0) ? x : ((lay == 1) ? bufY : bufZ);
        float* accb = bufX;
        float* zb   = (lay == 1) ? bufZ : bufY;
        float* hout = zb;  // z is dead by finalize time

        for (int r = 0; r < RR; ++r) {
            const float* Wr  = Wl + (size_t)r * 128 * 128;
            const float* alr = aL + (size_t)r * FH;
            const float* arr = aR + (size_t)r * FH;

            gemm_k128<<<gemm_grid, 256, 0, stream>>>(hin, Wr, nullptr, zb, NN, 128, 128);
            elr_init<<<g_nh, 256, 0, stream>>>(zb, alr, arr, el, er);
            gat_agg<<<g_agg, 256, 0, stream>>>(rowptr + (size_t)r * NN, colarr,
                                               zb, el, er, accb, r > 0 ? 1 : 0);
        }
        finalize_k<<<g_nf, 256, 0, stream>>>(accb, bL, hout, (lay < 2) ? 1 : 0);
    }

    // final linear: [N x 128] @ [128 x 64] + blin
    gemm_k128<<<dim3(GEMM_GX, 1), 256, 0, stream>>>(bufY, Wlin, blin, out, NN, 64, 64);
}

// Round 7
// 1520.043 us; speedup vs baseline: 2.0942x; 1.2154x over previous
//
#include <hip/hip_runtime.h>
#include <math.h>

#define NN 100000
#define EE 400000
#define RR 3
#define HH 4
#define DD 32
#define FH 128   // H*D
#define OUTF 64

#define SN (RR * NN)
#define SB 1024
#define SNB ((SN + SB - 1) / SB)  // 293

using bf16x8 = __attribute__((ext_vector_type(8))) short;
using f32x4  = __attribute__((ext_vector_type(4))) float;

#define MFMA16(a, b, c) __builtin_amdgcn_mfma_f32_16x16x32_bf16(a, b, c, 0, 0, 0)

__device__ __forceinline__ unsigned short f2bf(float x) {
    unsigned int u = __float_as_uint(x);
    unsigned int r = (u + 0x7fffu + ((u >> 16) & 1u)) >> 16;
    return (unsigned short)r;
}
__device__ __forceinline__ float bf2f(unsigned short h) {
    return __uint_as_float(((unsigned int)h) << 16);
}

// ---------------- CSR build ----------------

__global__ __launch_bounds__(256) void zero_i(int* __restrict__ p, int n)
{
    int i = blockIdx.x * 256 + threadIdx.x;
    if (i < n) p[i] = 0;
}

__global__ __launch_bounds__(256) void count_k(const int* __restrict__ dst, int* __restrict__ deg)
{
    int i = blockIdx.x * 256 + threadIdx.x;
    if (i >= RR * EE) return;
    int r = i / EE;
    atomicAdd(&deg[r * NN + dst[i]], 1);
}

__global__ __launch_bounds__(256) void scan_s1(const int* __restrict__ in, int* __restrict__ part)
{
    __shared__ int lds[256];
    int b = blockIdx.x, t = threadIdx.x;
    int base = b * SB + t * 4;
    int s = 0;
    #pragma unroll
    for (int k = 0; k < 4; ++k) { int idx = base + k; if (idx < SN) s += in[idx]; }
    lds[t] = s; __syncthreads();
    for (int off = 128; off > 0; off >>= 1) {
        if (t < off) lds[t] += lds[t + off];
        __syncthreads();
    }
    if (t == 0) part[b] = lds[0];
}

__global__ __launch_bounds__(512) void scan_s2(int* __restrict__ part)
{
    __shared__ int lds[512];
    int t = threadIdx.x;
    lds[t] = (t < SNB) ? part[t] : 0;
    __syncthreads();
    for (int off = 1; off < 512; off <<= 1) {
        int add = (t >= off) ? lds[t - off] : 0;
        __syncthreads();
        lds[t] += add;
        __syncthreads();
    }
    if (t < SNB) part[t] = (t == 0) ? 0 : lds[t - 1];
}

__global__ __launch_bounds__(256) void scan_s3(const int* __restrict__ in, const int* __restrict__ part,
                                               int* __restrict__ out)
{
    __shared__ int lds[256];
    int b = blockIdx.x, t = threadIdx.x;
    int base = b * SB + t * 4;
    int v[4]; int s = 0;
    #pragma unroll
    for (int k = 0; k < 4; ++k) {
        v[k] = (base + k < SN) ? in[base + k] : 0;
        s += v[k];
    }
    lds[t] = s; __syncthreads();
    for (int off = 1; off < 256; off <<= 1) {
        int add = (t >= off) ? lds[t - off] : 0;
        __syncthreads();
        lds[t] += add;
        __syncthreads();
    }
    int run = part[b] + ((t == 0) ? 0 : lds[t - 1]);
    #pragma unroll
    for (int k = 0; k < 4; ++k) {
        if (base + k < SN) out[base + k] = run;
        run += v[k];
    }
    if (b == 0 && t == 0) out[SN] = RR * EE;
}

__global__ __launch_bounds__(256) void copy_i(const int* __restrict__ a, int* __restrict__ b, int n)
{
    int i = blockIdx.x * 256 + threadIdx.x;
    if (i < n) b[i] = a[i];
}

__global__ __launch_bounds__(256) void scatter_k(const int* __restrict__ src, const int* __restrict__ dst,
                                                 int* __restrict__ cursor, int* __restrict__ col)
{
    int i = blockIdx.x * 256 + threadIdx.x;
    if (i >= RR * EE) return;
    int r = i / EE;
    int slot = atomicAdd(&cursor[r * NN + dst[i]], 1);
    col[slot] = src[i];
}

// ---------------- weight prep: BT[g] = split(transpose(augment(W_g))) ----------------
// Layout per g: BT + g*2*144*128 : [hi 144x128][lo 144x128] bf16 (row = output col, contiguous K)
// 8 blocks per g.
__global__ __launch_bounds__(256) void makeB(
    const float* __restrict__ W0, const float* __restrict__ al0, const float* __restrict__ ar0,
    const float* __restrict__ W12, const float* __restrict__ al12, const float* __restrict__ ar12,
    const float* __restrict__ Wlin, unsigned short* __restrict__ bt)
{
    int g = blockIdx.x >> 3;
    int sub = blockIdx.x & 7;
    const float *W, *al = nullptr, *ar = nullptr;
    if (g < 9) {
        int lay = g / 3, r = g % 3;
        W  = lay ? W12  + (size_t)((lay - 1) * RR + r) * 16384 : W0  + (size_t)r * 16384;
        al = lay ? al12 + (size_t)((lay - 1) * RR + r) * 128   : al0 + (size_t)r * 128;
        ar = lay ? ar12 + (size_t)((lay - 1) * RR + r) * 128   : ar0 + (size_t)r * 128;
    } else {
        W = Wlin;
    }
    unsigned short* hi = bt + (size_t)g * 2 * 144 * 128;
    unsigned short* lo = hi + 144 * 128;
    for (int idx = sub * 256 + threadIdx.x; idx < 144 * 128; idx += 2048) {
        int c = idx >> 7;     // augmented output col 0..143
        int k = idx & 127;
        float v = 0.f;
        if (g < 9) {
            if (c < 128) v = W[k * 128 + c];
            else if (c < 132) {
                int h = c - 128;
                for (int d = 0; d < DD; ++d) v += W[k * 128 + h * DD + d] * al[h * DD + d];
            } else if (c < 136) {
                int h = c - 132;
                for (int d = 0; d < DD; ++d) v += W[k * 128 + h * DD + d] * ar[h * DD + d];
            }
        } else {
            if (c < OUTF) v = W[k * OUTF + c];
        }
        unsigned short h16 = f2bf(v);
        hi[idx] = h16;
        lo[idx] = f2bf(v - bf2f(h16));
    }
}

// fp32 [N][128] -> bf16 hi/lo split (used for x and for each layer's h)
__global__ __launch_bounds__(256) void split_k(const float* __restrict__ in,
                                               unsigned short* __restrict__ A1,
                                               unsigned short* __restrict__ A2)
{
    int i = blockIdx.x * 256 + threadIdx.x;   // 1 thread = 4 elems
    if (i >= NN * FH / 4) return;
    float4 v = *(const float4*)&in[i * 4];
    ushort4 h, l;
    h.x = f2bf(v.x); l.x = f2bf(v.x - bf2f(h.x));
    h.y = f2bf(v.y); l.y = f2bf(v.y - bf2f(h.y));
    h.z = f2bf(v.z); l.z = f2bf(v.z - bf2f(h.z));
    h.w = f2bf(v.w); l.w = f2bf(v.w - bf2f(h.w));
    *(ushort4*)&A1[i * 4] = h;
    *(ushort4*)&A2[i * 4] = l;
}

// ---------------- split-bf16 MFMA GEMM ----------------
// C = (A1+A2) @ (B1+B2) ~= A1B1 + A1B2 + A2B1.  A: [M][128] bf16 pair.
// BT: [hi 144x128][lo 144x128] (row-per-output-col, contiguous K).
// AUG mode (NT=9): writes z [M][128], el/er [M][4] from cols 128..135.
// OUT mode (NT=4): writes outp [M][64] + bias.
template <int NT, bool AUG>
__global__ __launch_bounds__(256) void gemm_mfma(
    const unsigned short* __restrict__ A1, const unsigned short* __restrict__ A2,
    const unsigned short* __restrict__ BT,
    float* __restrict__ z, float* __restrict__ el, float* __restrict__ er,
    const float* __restrict__ bias, float* __restrict__ outp, int M)
{
    const int lane = threadIdx.x & 63;
    const int wid  = threadIdx.x >> 6;
    const int row0 = blockIdx.x * 64 + wid * 16;
    const int arow = min(row0 + (lane & 15), M - 1);
    const int koff = (lane >> 4) * 8;
    const unsigned short* BT1 = BT;
    const unsigned short* BT2 = BT + 144 * 128;

    f32x4 acc[NT];
    #pragma unroll
    for (int j = 0; j < NT; ++j) acc[j] = (f32x4){0.f, 0.f, 0.f, 0.f};

    #pragma unroll
    for (int kk = 0; kk < 4; ++kk) {
        const int ak = kk * 32 + koff;
        bf16x8 a1 = *(const bf16x8*)(A1 + (size_t)arow * 128 + ak);
        bf16x8 a2 = *(const bf16x8*)(A2 + (size_t)arow * 128 + ak);
        #pragma unroll
        for (int j = 0; j < NT; ++j) {
            const int bro = (j * 16 + (lane & 15)) * 128 + ak;
            bf16x8 b1 = *(const bf16x8*)(BT1 + bro);
            bf16x8 b2 = *(const bf16x8*)(BT2 + bro);
            acc[j] = MFMA16(a2, b1, acc[j]);
            acc[j] = MFMA16(a1, b2, acc[j]);
            acc[j] = MFMA16(a1, b1, acc[j]);
        }
    }

    const int crow0 = row0 + ((lane >> 4) << 2);
    const int ccol  = lane & 15;
    #pragma unroll
    for (int q = 0; q < 4; ++q) {
        int row = crow0 + q;
        if (row >= M) continue;
        if (AUG) {
            #pragma unroll
            for (int j = 0; j < 8; ++j)
                z[(size_t)row * 128 + j * 16 + ccol] = acc[j][q];
            float av = acc[8][q];
            if (ccol < 4)      el[row * 4 + ccol] = av;
            else if (ccol < 8) er[row * 4 + ccol - 4] = av;
        } else {
            #pragma unroll
            for (int j = 0; j < 4; ++j)
                outp[(size_t)row * 64 + j * 16 + ccol] = acc[j][q] + bias[j * 16 + ccol];
        }
    }
}

// ---------------- fused softmax + aggregation (single pass, no atomics) ----------------
// mode 0: acc = a ; mode 1: acc += a ;
// mode 2: acc = [(acc + a + bias)/3, optional leaky]  (fp32 h, in-place same-thread RMW)
__global__ __launch_bounds__(256) void gat_agg(
    const int* __restrict__ rowptr, const int* __restrict__ col,
    const float* __restrict__ z,
    const float* __restrict__ el, const float* __restrict__ er,
    float* __restrict__ acc, int mode,
    const float* __restrict__ bL, int act)
{
    int wave = (blockIdx.x * 256 + threadIdx.x) >> 6;
    int lane = threadIdx.x & 63;
    if (wave >= NN) return;
    const int d  = wave;
    const int hp = lane >> 4;
    const int f0 = lane * 2;
    const int p0 = rowptr[d], p1 = rowptr[d + 1];

    const float erh = er[d * HH + hp];
    float ssum = 0.f;
    float2 a = make_float2(0.f, 0.f);
    for (int e = p0; e < p1; ++e) {
        int s = col[e];
        float v = el[s * HH + hp] + erh;
        v = v > 0.f ? v : 0.2f * v;
        float p = __expf(v);
        ssum += p;
        float2 zr = *(const float2*)&z[(size_t)s * FH + f0];
        a.x += p * zr.x;
        a.y += p * zr.y;
    }
    float inv = (ssum > 0.f) ? 1.f / ssum : 0.f;
    a.x *= inv; a.y *= inv;

    float2* ap = (float2*)&acc[(size_t)d * FH + f0];
    if (mode == 0) {
        *ap = a;
    } else if (mode == 1) {
        float2 o = *ap;
        o.x += a.x; o.y += a.y;
        *ap = o;
    } else {
        float2 o = *ap;
        float bx = bL[f0]     + bL[FH + f0]     + bL[2 * FH + f0];
        float by = bL[f0 + 1] + bL[FH + f0 + 1] + bL[2 * FH + f0 + 1];
        float vx = (o.x + a.x + bx) * (1.f / 3.f);
        float vy = (o.y + a.y + by) * (1.f / 3.f);
        if (act) {
            vx = vx > 0.f ? vx : 0.01f * vx;
            vy = vy > 0.f ? vy : 0.01f * vy;
        }
        o.x = vx; o.y = vy;
        *ap = o;
    }
}

extern "C" void kernel_launch(void* const* d_in, const int* in_sizes, int n_in,
                              void* d_out, int out_size, void* d_ws, size_t ws_size,
                              hipStream_t stream)
{
    const float* x    = (const float*)d_in[0];
    const int*   src  = (const int*)d_in[1];
    const int*   dst  = (const int*)d_in[2];
    const float* W0   = (const float*)d_in[3];
    const float* al0  = (const float*)d_in[4];
    const float* ar0  = (const float*)d_in[5];
    const float* b0   = (const float*)d_in[6];
    const float* W12  = (const float*)d_in[7];
    const float* al12 = (const float*)d_in[8];
    const float* ar12 = (const float*)d_in[9];
    const float* b12  = (const float*)d_in[10];
    const float* Wlin = (const float*)d_in[11];
    const float* blin = (const float*)d_in[12];
    float* out = (float*)d_out;

    char* ws = (char*)d_ws;
    size_t off = 0;
    auto alloc = [&](size_t bytes) {
        void* p = ws + off;
        off += (bytes + 255) & ~(size_t)255;
        return p;
    };
    unsigned short* A1 = (unsigned short*)alloc((size_t)NN * FH * 2);  // 25.6 MB
    unsigned short* A2 = (unsigned short*)alloc((size_t)NN * FH * 2);  // 25.6 MB
    float* zbuf = (float*)alloc((size_t)NN * FH * 4);                  // 51.2 MB
    float* accb = (float*)alloc((size_t)NN * FH * 4);                  // 51.2 MB (acc -> h in-place)
    float* el   = (float*)alloc((size_t)NN * HH * 4);
    float* er   = (float*)alloc((size_t)NN * HH * 4);
    unsigned short* bt = (unsigned short*)alloc((size_t)10 * 2 * 144 * 128 * 2);
    int* rowptr = (int*)alloc((size_t)(SN + 1) * 4);
    int* cursor = (int*)alloc((size_t)SN * 4);
    int* colarr = (int*)alloc((size_t)RR * EE * 4);
    int* part   = (int*)alloc((size_t)SNB * 4);

    const int g_3e  = (RR * EE + 255) / 256;
    const int g_3n  = (SN + 255) / 256;
    const int g_agg = NN / 4;                    // 25000
    const int g_gm  = (NN + 63) / 64;            // 1563
    const int g_sx  = (NN * FH / 4 + 255) / 256; // 12500

    // ---- CSR (shared by all layers) ----
    zero_i<<<g_3n, 256, 0, stream>>>(cursor, SN);
    count_k<<<g_3e, 256, 0, stream>>>(dst, cursor);
    scan_s1<<<SNB, 256, 0, stream>>>(cursor, part);
    scan_s2<<<1, 512, 0, stream>>>(part);
    scan_s3<<<SNB, 256, 0, stream>>>(cursor, part, rowptr);
    copy_i<<<g_3n, 256, 0, stream>>>(rowptr, cursor, SN);
    scatter_k<<<g_3e, 256, 0, stream>>>(src, dst, cursor, colarr);

    // ---- weight prep ----
    makeB<<<80, 256, 0, stream>>>(W0, al0, ar0, W12, al12, ar12, Wlin, bt);

    for (int lay = 0; lay < 3; ++lay) {
        const float* bL = (lay == 0) ? b0 : b12 + (size_t)(lay - 1) * RR * FH;
        const float* hin = (lay == 0) ? x : accb;   // fp32 h of previous layer

        split_k<<<g_sx, 256, 0, stream>>>(hin, A1, A2);

        for (int r = 0; r < RR; ++r) {
            const unsigned short* btg = bt + (size_t)(lay * RR + r) * 2 * 144 * 128;
            gemm_mfma<9, true><<<g_gm, 256, 0, stream>>>(
                A1, A2, btg, zbuf, el, er, nullptr, nullptr, NN);
            int mode = (r == 0) ? 0 : (r == 2 ? 2 : 1);
            gat_agg<<<g_agg, 256, 0, stream>>>(
                rowptr + (size_t)r * NN, colarr, zbuf, el, er, accb,
                mode, bL, (lay < 2) ? 1 : 0);
        }
    }

    // final linear: [N x 128] @ [128 x 64] + blin
    split_k<<<g_sx, 256, 0, stream>>>(accb, A1, A2);
    gemm_mfma<4, false><<<g_gm, 256, 0, stream>>>(
        A1, A2, bt + (size_t)9 * 2 * 144 * 128, nullptr, nullptr, nullptr, blin, out, NN);
}

// Round 9
// 1389.973 us; speedup vs baseline: 2.2902x; 1.0936x over previous
//
#include <hip/hip_runtime.h>
#include <math.h>

#define NN 100000
#define EE 400000
#define RR 3
#define HH 4
#define DD 32
#define FH 128   // H*D
#define OUTF 64

#define SN (RR * NN)
#define SB 1024
#define SNB ((SN + SB - 1) / SB)  // 293
#define NCH 128                   // edge chunks for bucketed CSR build
#define ECHUNK (RR * EE / NCH)    // 9375
#define RANGE (SN / 8)            // 37500 flattened (r,node) keys per XCD bucket

using bf16x8 = __attribute__((ext_vector_type(8))) short;
using f32x4  = __attribute__((ext_vector_type(4))) float;

#define MFMA16(a, b, c) __builtin_amdgcn_mfma_f32_16x16x32_bf16(a, b, c, 0, 0, 0)

__device__ __forceinline__ unsigned short f2bf(float x) {
    unsigned int u = __float_as_uint(x);
    unsigned int r = (u + 0x7fffu + ((u >> 16) & 1u)) >> 16;
    return (unsigned short)r;
}
__device__ __forceinline__ float bf2f(unsigned short h) {
    return __uint_as_float(((unsigned int)h) << 16);
}

// ---------------- CSR build ----------------

__global__ __launch_bounds__(256) void zero_i(int* __restrict__ p, int n)
{
    int i = blockIdx.x * 256 + threadIdx.x;
    if (i < n) p[i] = 0;
}

// XCD-bucketed degree count: blockIdx&7 = key-range bucket (XCD-local L2 atomics),
// blockIdx>>3 = edge chunk. Correct for ANY block->XCD mapping.
__global__ __launch_bounds__(256) void count8(const int* __restrict__ dst, int* __restrict__ deg)
{
    const int g  = blockIdx.x & 7;
    const int c  = blockIdx.x >> 3;
    const int lo = g * RANGE, hi = lo + RANGE;
    const int e0 = c * ECHUNK, e1 = e0 + ECHUNK;
    for (int i = e0 + threadIdx.x; i < e1; i += 256) {
        int r = (i >= 2 * EE) ? 2 : (i >= EE ? 1 : 0);
        int key = r * NN + dst[i];
        if (key >= lo && key < hi) atomicAdd(&deg[key], 1);
    }
}

__global__ __launch_bounds__(256) void scan_s1(const int* __restrict__ in, int* __restrict__ part)
{
    __shared__ int lds[256];
    int b = blockIdx.x, t = threadIdx.x;
    int base = b * SB + t * 4;
    int s = 0;
    #pragma unroll
    for (int k = 0; k < 4; ++k) { int idx = base + k; if (idx < SN) s += in[idx]; }
    lds[t] = s; __syncthreads();
    for (int off = 128; off > 0; off >>= 1) {
        if (t < off) lds[t] += lds[t + off];
        __syncthreads();
    }
    if (t == 0) part[b] = lds[0];
}

__global__ __launch_bounds__(512) void scan_s2(int* __restrict__ part)
{
    __shared__ int lds[512];
    int t = threadIdx.x;
    lds[t] = (t < SNB) ? part[t] : 0;
    __syncthreads();
    for (int off = 1; off < 512; off <<= 1) {
        int add = (t >= off) ? lds[t - off] : 0;
        __syncthreads();
        lds[t] += add;
        __syncthreads();
    }
    if (t < SNB) part[t] = (t == 0) ? 0 : lds[t - 1];
}

__global__ __launch_bounds__(256) void scan_s3(const int* __restrict__ in, const int* __restrict__ part,
                                               int* __restrict__ out)
{
    __shared__ int lds[256];
    int b = blockIdx.x, t = threadIdx.x;
    int base = b * SB + t * 4;
    int v[4]; int s = 0;
    #pragma unroll
    for (int k = 0; k < 4; ++k) {
        v[k] = (base + k < SN) ? in[base + k] : 0;
        s += v[k];
    }
    lds[t] = s; __syncthreads();
    for (int off = 1; off < 256; off <<= 1) {
        int add = (t >= off) ? lds[t - off] : 0;
        __syncthreads();
        lds[t] += add;
        __syncthreads();
    }
    int run = part[b] + ((t == 0) ? 0 : lds[t - 1]);
    #pragma unroll
    for (int k = 0; k < 4; ++k) {
        if (base + k < SN) out[base + k] = run;
        run += v[k];
    }
    if (b == 0 && t == 0) out[SN] = RR * EE;
}

__global__ __launch_bounds__(256) void copy_i(const int* __restrict__ a, int* __restrict__ b, int n)
{
    int i = blockIdx.x * 256 + threadIdx.x;
    if (i < n) b[i] = a[i];
}

// XCD-bucketed scatter: same bucketing as count8; col writes land in a
// range-private ~600KB window (fits one XCD L2) instead of thrashing 4.8MB.
__global__ __launch_bounds__(256) void scatter8(const int* __restrict__ src, const int* __restrict__ dst,
                                                int* __restrict__ cursor, int* __restrict__ col)
{
    const int g  = blockIdx.x & 7;
    const int c  = blockIdx.x >> 3;
    const int lo = g * RANGE, hi = lo + RANGE;
    const int e0 = c * ECHUNK, e1 = e0 + ECHUNK;
    for (int i = e0 + threadIdx.x; i < e1; i += 256) {
        int s = src[i];                 // coalesced stream read
        int r = (i >= 2 * EE) ? 2 : (i >= EE ? 1 : 0);
        int key = r * NN + dst[i];
        if (key >= lo && key < hi) {
            int slot = atomicAdd(&cursor[key], 1);
            col[slot] = s;
        }
    }
}

// ---------------- weight prep: BT[g] = split(transpose(augment(W_g))) ----------------
// Layout per g: BT + g*2*144*128 : [hi 144x128][lo 144x128] bf16 (row = output col, contiguous K)
__global__ __launch_bounds__(256) void makeB(
    const float* __restrict__ W0, const float* __restrict__ al0, const float* __restrict__ ar0,
    const float* __restrict__ W12, const float* __restrict__ al12, const float* __restrict__ ar12,
    const float* __restrict__ Wlin, unsigned short* __restrict__ bt)
{
    int g = blockIdx.x >> 3;
    int sub = blockIdx.x & 7;
    const float *W, *al = nullptr, *ar = nullptr;
    if (g < 9) {
        int lay = g / 3, r = g % 3;
        W  = lay ? W12  + (size_t)((lay - 1) * RR + r) * 16384 : W0  + (size_t)r * 16384;
        al = lay ? al12 + (size_t)((lay - 1) * RR + r) * 128   : al0 + (size_t)r * 128;
        ar = lay ? ar12 + (size_t)((lay - 1) * RR + r) * 128   : ar0 + (size_t)r * 128;
    } else {
        W = Wlin;
    }
    unsigned short* hi = bt + (size_t)g * 2 * 144 * 128;
    unsigned short* lo = hi + 144 * 128;
    for (int idx = sub * 256 + threadIdx.x; idx < 144 * 128; idx += 2048) {
        int c = idx >> 7;     // augmented output col 0..143
        int k = idx & 127;
        float v = 0.f;
        if (g < 9) {
            if (c < 128) v = W[k * 128 + c];
            else if (c < 132) {
                int h = c - 128;
                for (int d = 0; d < DD; ++d) v += W[k * 128 + h * DD + d] * al[h * DD + d];
            } else if (c < 136) {
                int h = c - 132;
                for (int d = 0; d < DD; ++d) v += W[k * 128 + h * DD + d] * ar[h * DD + d];
            }
        } else {
            if (c < OUTF) v = W[k * OUTF + c];
        }
        unsigned short h16 = f2bf(v);
        hi[idx] = h16;
        lo[idx] = f2bf(v - bf2f(h16));
    }
}

// ---------------- split-bf16 MFMA GEMM, fp32 A with in-register hi/lo split ----------------
// C = A @ (B1+B2) via Markidis: A=hi+lo in-register; 3 MFMAs per tile.
// AUG (NT=9): writes z [M][128] bf16 + el/er [M][4] fp32 (aug cols 128..135).
// OUT (NT=4): writes outp [M][64] fp32 + bias.
template <int NT, bool AUG>
__global__ __launch_bounds__(256) void gemm_f32a(
    const float* __restrict__ A, const unsigned short* __restrict__ BT,
    unsigned short* __restrict__ z, float* __restrict__ el, float* __restrict__ er,
    const float* __restrict__ bias, float* __restrict__ outp, int M)
{
    const int lane = threadIdx.x & 63;
    const int wid  = threadIdx.x >> 6;
    const int row0 = blockIdx.x * 64 + wid * 16;
    const int arow = min(row0 + (lane & 15), M - 1);
    const int koff = (lane >> 4) * 8;
    const unsigned short* BT1 = BT;
    const unsigned short* BT2 = BT + 144 * 128;

    f32x4 acc[NT];
    #pragma unroll
    for (int j = 0; j < NT; ++j) acc[j] = (f32x4){0.f, 0.f, 0.f, 0.f};

    #pragma unroll
    for (int kk = 0; kk < 4; ++kk) {
        const int ak = kk * 32 + koff;
        const float* ap = A + (size_t)arow * 128 + ak;
        float4 v0 = *(const float4*)ap;
        float4 v1 = *(const float4*)(ap + 4);
        float vv[8] = {v0.x, v0.y, v0.z, v0.w, v1.x, v1.y, v1.z, v1.w};
        bf16x8 a1, a2;
        #pragma unroll
        for (int t = 0; t < 8; ++t) {
            unsigned short h = f2bf(vv[t]);
            a1[t] = (short)h;
            a2[t] = (short)f2bf(vv[t] - bf2f(h));
        }
        #pragma unroll
        for (int j = 0; j < NT; ++j) {
            const int bro = (j * 16 + (lane & 15)) * 128 + ak;
            bf16x8 b1 = *(const bf16x8*)(BT1 + bro);
            bf16x8 b2 = *(const bf16x8*)(BT2 + bro);
            acc[j] = MFMA16(a2, b1, acc[j]);
            acc[j] = MFMA16(a1, b2, acc[j]);
            acc[j] = MFMA16(a1, b1, acc[j]);
        }
    }

    const int crow0 = row0 + ((lane >> 4) << 2);
    const int ccol  = lane & 15;
    #pragma unroll
    for (int q = 0; q < 4; ++q) {
        int row = crow0 + q;
        if (row >= M) continue;
        if (AUG) {
            unsigned short* zr = z + (size_t)row * 128;
            #pragma unroll
            for (int j = 0; j < 8; ++j)
                zr[j * 16 + ccol] = f2bf(acc[j][q]);
            float av = acc[8][q];
            if (ccol < 4)      el[row * 4 + ccol] = av;
            else if (ccol < 8) er[row * 4 + ccol - 4] = av;
        } else {
            #pragma unroll
            for (int j = 0; j < 4; ++j)
                outp[(size_t)row * 64 + j * 16 + ccol] = acc[j][q] + bias[j * 16 + ccol];
        }
    }
}

// ---------------- fused softmax + aggregation (single pass, no atomics) ----------------
// mode 0: hout = a ; mode 1: hout += a ;
// mode 2: hout = [(hout + a + bias)/3, optional leaky]  (same-thread RMW only)
__global__ __launch_bounds__(256) void gat_agg(
    const int* __restrict__ rowptr, const int* __restrict__ col,
    const unsigned short* __restrict__ z,     // [NN][128] bf16
    const float* __restrict__ el, const float* __restrict__ er,
    float* __restrict__ hout, int mode,
    const float* __restrict__ bL, int act)
{
    int wave = (blockIdx.x * 256 + threadIdx.x) >> 6;
    int lane = threadIdx.x & 63;
    if (wave >= NN) return;
    const int d  = wave;
    const int hp = lane >> 4;
    const int f0 = lane * 2;
    const int p0 = rowptr[d], p1 = rowptr[d + 1];

    const float erh = er[d * HH + hp];
    float ssum = 0.f;
    float ax = 0.f, ay = 0.f;
    for (int e = p0; e < p1; ++e) {
        int s = col[e];
        float v = el[s * HH + hp] + erh;
        v = v > 0.f ? v : 0.2f * v;
        float p = __expf(v);
        ssum += p;
        ushort2 zv = *(const ushort2*)&z[(size_t)s * FH + f0];
        ax += p * bf2f(zv.x);
        ay += p * bf2f(zv.y);
    }
    float inv = (ssum > 0.f) ? 1.f / ssum : 0.f;
    ax *= inv; ay *= inv;

    float2* ap = (float2*)&hout[(size_t)d * FH + f0];
    if (mode == 0) {
        *ap = make_float2(ax, ay);
    } else if (mode == 1) {
        float2 o = *ap;
        o.x += ax; o.y += ay;
        *ap = o;
    } else {
        float2 o = *ap;
        float bx = bL[f0]     + bL[FH + f0]     + bL[2 * FH + f0];
        float by = bL[f0 + 1] + bL[FH + f0 + 1] + bL[2 * FH + f0 + 1];
        float vx = (o.x + ax + bx) * (1.f / 3.f);
        float vy = (o.y + ay + by) * (1.f / 3.f);
        if (act) {
            vx = vx > 0.f ? vx : 0.01f * vx;
            vy = vy > 0.f ? vy : 0.01f * vy;
        }
        *ap = make_float2(vx, vy);
    }
}

extern "C" void kernel_launch(void* const* d_in, const int* in_sizes, int n_in,
                              void* d_out, int out_size, void* d_ws, size_t ws_size,
                              hipStream_t stream)
{
    const float* x    = (const float*)d_in[0];
    const int*   src  = (const int*)d_in[1];
    const int*   dst  = (const int*)d_in[2];
    const float* W0   = (const float*)d_in[3];
    const float* al0  = (const float*)d_in[4];
    const float* ar0  = (const float*)d_in[5];
    const float* b0   = (const float*)d_in[6];
    const float* W12  = (const float*)d_in[7];
    const float* al12 = (const float*)d_in[8];
    const float* ar12 = (const float*)d_in[9];
    const float* b12  = (const float*)d_in[10];
    const float* Wlin = (const float*)d_in[11];
    const float* blin = (const float*)d_in[12];
    float* out = (float*)d_out;

    char* ws = (char*)d_ws;
    size_t off = 0;
    auto alloc = [&](size_t bytes) {
        void* p = ws + off;
        off += (bytes + 255) & ~(size_t)255;
        return p;
    };
    unsigned short* zb = (unsigned short*)alloc((size_t)NN * FH * 2);  // 25.6 MB bf16
    float* hb0  = (float*)alloc((size_t)NN * FH * 4);                  // 51.2 MB
    float* hb1  = (float*)alloc((size_t)NN * FH * 4);                  // 51.2 MB
    float* el   = (float*)alloc((size_t)NN * HH * 4);
    float* er   = (float*)alloc((size_t)NN * HH * 4);
    unsigned short* bt = (unsigned short*)alloc((size_t)10 * 2 * 144 * 128 * 2);
    int* rowptr = (int*)alloc((size_t)(SN + 1) * 4);
    int* cursor = (int*)alloc((size_t)SN * 4);
    int* colarr = (int*)alloc((size_t)RR * EE * 4);
    int* part   = (int*)alloc((size_t)SNB * 4);
    // total ~139 MB — under the 165 MB envelope proven by r4/r7

    const int g_3n  = (SN + 255) / 256;
    const int g_agg = NN / 4;                    // 25000
    const int g_gm  = (NN + 63) / 64;            // 1563

    // ---- CSR (shared by all layers), XCD-bucketed build ----
    zero_i<<<g_3n, 256, 0, stream>>>(cursor, SN);
    count8<<<8 * NCH, 256, 0, stream>>>(dst, cursor);
    scan_s1<<<SNB, 256, 0, stream>>>(cursor, part);
    scan_s2<<<1, 512, 0, stream>>>(part);
    scan_s3<<<SNB, 256, 0, stream>>>(cursor, part, rowptr);
    copy_i<<<g_3n, 256, 0, stream>>>(rowptr, cursor, SN);
    scatter8<<<8 * NCH, 256, 0, stream>>>(src, dst, cursor, colarr);

    // ---- weight prep ----
    makeB<<<80, 256, 0, stream>>>(W0, al0, ar0, W12, al12, ar12, Wlin, bt);

    // layer l: reads hin (x or previous h), writes hout (ping-pong; never aliased)
    for (int lay = 0; lay < 3; ++lay) {
        const float* bL  = (lay == 0) ? b0 : b12 + (size_t)(lay - 1) * RR * FH;
        const float* hin = (lay == 0) ? x : ((lay == 1) ? hb0 : hb1);
        float* hout      = (lay & 1) ? hb1 : hb0;

        for (int r = 0; r < RR; ++r) {
            const unsigned short* btg = bt + (size_t)(lay * RR + r) * 2 * 144 * 128;
            gemm_f32a<9, true><<<g_gm, 256, 0, stream>>>(
                hin, btg, zb, el, er, nullptr, nullptr, NN);
            int mode = (r == 0) ? 0 : (r == 2 ? 2 : 1);
            gat_agg<<<g_agg, 256, 0, stream>>>(
                rowptr + (size_t)r * NN, colarr, zb, el, er, hout,
                mode, bL, (lay < 2) ? 1 : 0);
        }
    }

    // final linear: [N x 128] @ [128 x 64] + blin   (reads hb0 = layer-2 output)
    gemm_f32a<4, false><<<g_gm, 256, 0, stream>>>(
        hb0, bt + (size_t)9 * 2 * 144 * 128, nullptr, nullptr, nullptr, blin, out, NN);
}

// Round 10
// 1098.443 us; speedup vs baseline: 2.8980x; 1.2654x over previous
//
#include <hip/hip_runtime.h>
#include <math.h>

#define NN 100000
#define EE 400000
#define RR 3
#define HH 4
#define DD 32
#define FH 128   // H*D
#define OUTF 64

#define SN (RR * NN)
#define SB 1024
#define SNB ((SN + SB - 1) / SB)  // 293
#define NCH 128                   // edge chunks for bucketed CSR build
#define ECHUNK (RR * EE / NCH)    // 9375
#define RANGE (SN / 8)            // 37500 flattened (r,node) keys per XCD bucket

using bf16x8 = __attribute__((ext_vector_type(8))) short;
using f32x4  = __attribute__((ext_vector_type(4))) float;

#define MFMA16(a, b, c) __builtin_amdgcn_mfma_f32_16x16x32_bf16(a, b, c, 0, 0, 0)

__device__ __forceinline__ unsigned short f2bf(float x) {
    unsigned int u = __float_as_uint(x);
    unsigned int r = (u + 0x7fffu + ((u >> 16) & 1u)) >> 16;
    return (unsigned short)r;
}
__device__ __forceinline__ float bf2f(unsigned short h) {
    return __uint_as_float(((unsigned int)h) << 16);
}

// ---------------- CSR build ----------------

__global__ __launch_bounds__(256) void zero_i(int* __restrict__ p, int n)
{
    int i = blockIdx.x * 256 + threadIdx.x;
    if (i < n) p[i] = 0;
}

// XCD-bucketed degree count: blockIdx&7 = key-range bucket, blockIdx>>3 = edge chunk.
__global__ __launch_bounds__(256) void count8(const int* __restrict__ dst, int* __restrict__ deg)
{
    const int g  = blockIdx.x & 7;
    const int c  = blockIdx.x >> 3;
    const int lo = g * RANGE, hi = lo + RANGE;
    const int e0 = c * ECHUNK, e1 = e0 + ECHUNK;
    for (int i = e0 + threadIdx.x; i < e1; i += 256) {
        int r = (i >= 2 * EE) ? 2 : (i >= EE ? 1 : 0);
        int key = r * NN + dst[i];
        if (key >= lo && key < hi) atomicAdd(&deg[key], 1);
    }
}

__global__ __launch_bounds__(256) void scan_s1(const int* __restrict__ in, int* __restrict__ part)
{
    __shared__ int lds[256];
    int b = blockIdx.x, t = threadIdx.x;
    int base = b * SB + t * 4;
    int s = 0;
    #pragma unroll
    for (int k = 0; k < 4; ++k) { int idx = base + k; if (idx < SN) s += in[idx]; }
    lds[t] = s; __syncthreads();
    for (int off = 128; off > 0; off >>= 1) {
        if (t < off) lds[t] += lds[t + off];
        __syncthreads();
    }
    if (t == 0) part[b] = lds[0];
}

__global__ __launch_bounds__(512) void scan_s2(int* __restrict__ part)
{
    __shared__ int lds[512];
    int t = threadIdx.x;
    lds[t] = (t < SNB) ? part[t] : 0;
    __syncthreads();
    for (int off = 1; off < 512; off <<= 1) {
        int add = (t >= off) ? lds[t - off] : 0;
        __syncthreads();
        lds[t] += add;
        __syncthreads();
    }
    if (t < SNB) part[t] = (t == 0) ? 0 : lds[t - 1];
}

__global__ __launch_bounds__(256) void scan_s3(const int* __restrict__ in, const int* __restrict__ part,
                                               int* __restrict__ out)
{
    __shared__ int lds[256];
    int b = blockIdx.x, t = threadIdx.x;
    int base = b * SB + t * 4;
    int v[4]; int s = 0;
    #pragma unroll
    for (int k = 0; k < 4; ++k) {
        v[k] = (base + k < SN) ? in[base + k] : 0;
        s += v[k];
    }
    lds[t] = s; __syncthreads();
    for (int off = 1; off < 256; off <<= 1) {
        int add = (t >= off) ? lds[t - off] : 0;
        __syncthreads();
        lds[t] += add;
        __syncthreads();
    }
    int run = part[b] + ((t == 0) ? 0 : lds[t - 1]);
    #pragma unroll
    for (int k = 0; k < 4; ++k) {
        if (base + k < SN) out[base + k] = run;
        run += v[k];
    }
    if (b == 0 && t == 0) out[SN] = RR * EE;
}

__global__ __launch_bounds__(256) void copy_i(const int* __restrict__ a, int* __restrict__ b, int n)
{
    int i = blockIdx.x * 256 + threadIdx.x;
    if (i < n) b[i] = a[i];
}

__global__ __launch_bounds__(256) void scatter8(const int* __restrict__ src, const int* __restrict__ dst,
                                                int* __restrict__ cursor, int* __restrict__ col)
{
    const int g  = blockIdx.x & 7;
    const int c  = blockIdx.x >> 3;
    const int lo = g * RANGE, hi = lo + RANGE;
    const int e0 = c * ECHUNK, e1 = e0 + ECHUNK;
    for (int i = e0 + threadIdx.x; i < e1; i += 256) {
        int s = src[i];
        int r = (i >= 2 * EE) ? 2 : (i >= EE ? 1 : 0);
        int key = r * NN + dst[i];
        if (key >= lo && key < hi) {
            int slot = atomicAdd(&cursor[key], 1);
            col[slot] = s;
        }
    }
}

// ---------------- weight prep: BT[g] = split(transpose(augment(W_g))) ----------------
__global__ __launch_bounds__(256) void makeB(
    const float* __restrict__ W0, const float* __restrict__ al0, const float* __restrict__ ar0,
    const float* __restrict__ W12, const float* __restrict__ al12, const float* __restrict__ ar12,
    const float* __restrict__ Wlin, unsigned short* __restrict__ bt)
{
    int g = blockIdx.x >> 3;
    int sub = blockIdx.x & 7;
    const float *W, *al = nullptr, *ar = nullptr;
    if (g < 9) {
        int lay = g / 3, r = g % 3;
        W  = lay ? W12  + (size_t)((lay - 1) * RR + r) * 16384 : W0  + (size_t)r * 16384;
        al = lay ? al12 + (size_t)((lay - 1) * RR + r) * 128   : al0 + (size_t)r * 128;
        ar = lay ? ar12 + (size_t)((lay - 1) * RR + r) * 128   : ar0 + (size_t)r * 128;
    } else {
        W = Wlin;
    }
    unsigned short* hi = bt + (size_t)g * 2 * 144 * 128;
    unsigned short* lo = hi + 144 * 128;
    for (int idx = sub * 256 + threadIdx.x; idx < 144 * 128; idx += 2048) {
        int c = idx >> 7;     // augmented output col 0..143
        int k = idx & 127;
        float v = 0.f;
        if (g < 9) {
            if (c < 128) v = W[k * 128 + c];
            else if (c < 132) {
                int h = c - 128;
                for (int d = 0; d < DD; ++d) v += W[k * 128 + h * DD + d] * al[h * DD + d];
            } else if (c < 136) {
                int h = c - 132;
                for (int d = 0; d < DD; ++d) v += W[k * 128 + h * DD + d] * ar[h * DD + d];
            }
        } else {
            if (c < OUTF) v = W[k * OUTF + c];
        }
        unsigned short h16 = f2bf(v);
        hi[idx] = h16;
        lo[idx] = f2bf(v - bf2f(h16));
    }
}

// ---------------- split-bf16 MFMA GEMM with LDS-staged B ----------------
// C = A @ (B1+B2), A fp32 with in-register hi/lo Markidis split (3 MFMAs/tile).
// BT global: [hi 144x128][lo 144x128] bf16. Staged into 72KB LDS, XOR-swizzled
// (colb ^ (row&7)<<4) to kill the stride-256B 16-way bank conflict.
// AUG (NT=9): z [M][128] bf16 + el/er [M][4] fp32. OUT (NT=4): outp [M][64] + bias.
template <int NT, bool AUG>
__global__ __launch_bounds__(256) void gemm_f32a(
    const float* __restrict__ A, const unsigned short* __restrict__ BT,
    unsigned short* __restrict__ z, float* __restrict__ el, float* __restrict__ er,
    const float* __restrict__ bias, float* __restrict__ outp, int M)
{
    __shared__ unsigned short Bs[288 * 128];   // 72 KB, rows 0..143 hi, 144..287 lo

    const int lane = threadIdx.x & 63;
    const int wid  = threadIdx.x >> 6;

    // stage BT -> LDS (16B chunks), swizzled
    {
        const uint4* s4 = (const uint4*)BT;    // 4608 chunks of 16B
        for (int i = threadIdx.x; i < 4608; i += 256) {
            int bo  = i << 4;
            int row = bo >> 8;
            int cb  = bo & 255;
            *(uint4*)((char*)Bs + (row << 8) + (cb ^ ((row & 7) << 4))) = s4[i];
        }
    }
    __syncthreads();

    const int row0 = blockIdx.x * 64 + wid * 16;
    const int arow = min(row0 + (lane & 15), M - 1);
    const int koff = (lane >> 4) * 8;

    f32x4 acc[NT];
    #pragma unroll
    for (int j = 0; j < NT; ++j) acc[j] = (f32x4){0.f, 0.f, 0.f, 0.f};

    #pragma unroll
    for (int kk = 0; kk < 4; ++kk) {
        const int ak = kk * 32 + koff;
        const float* ap = A + (size_t)arow * 128 + ak;
        float4 v0 = *(const float4*)ap;
        float4 v1 = *(const float4*)(ap + 4);
        float vv[8] = {v0.x, v0.y, v0.z, v0.w, v1.x, v1.y, v1.z, v1.w};
        bf16x8 a1, a2;
        #pragma unroll
        for (int t = 0; t < 8; ++t) {
            unsigned short h = f2bf(vv[t]);
            a1[t] = (short)h;
            a2[t] = (short)f2bf(vv[t] - bf2f(h));
        }
        const int cb = ak * 2;                 // byte col within 256B row
        #pragma unroll
        for (int j = 0; j < NT; ++j) {
            const int r1 = j * 16 + (lane & 15);
            const int r2 = r1 + 144;           // same (row&7) as r1
            const int sw = cb ^ ((r1 & 7) << 4);
            bf16x8 b1 = *(const bf16x8*)((const char*)Bs + (r1 << 8) + sw);
            bf16x8 b2 = *(const bf16x8*)((const char*)Bs + (r2 << 8) + sw);
            acc[j] = MFMA16(a2, b1, acc[j]);
            acc[j] = MFMA16(a1, b2, acc[j]);
            acc[j] = MFMA16(a1, b1, acc[j]);
        }
    }

    const int crow0 = row0 + ((lane >> 4) << 2);
    const int ccol  = lane & 15;
    #pragma unroll
    for (int q = 0; q < 4; ++q) {
        int row = crow0 + q;
        if (row >= M) continue;
        if (AUG) {
            unsigned short* zr = z + (size_t)row * 128;
            #pragma unroll
            for (int j = 0; j < 8; ++j)
                zr[j * 16 + ccol] = f2bf(acc[j][q]);
            float av = acc[8][q];
            if (ccol < 4)      el[row * 4 + ccol] = av;
            else if (ccol < 8) er[row * 4 + ccol - 4] = av;
        } else {
            #pragma unroll
            for (int j = 0; j < 4; ++j)
                outp[(size_t)row * 64 + j * 16 + ccol] = acc[j][q] + bias[j * 16 + ccol];
        }
    }
}

// ---------------- fused softmax + aggregation (single pass, no atomics) ----------------
// mode 0: hout = a ; mode 1: hout += a ;
// mode 2: hout = [(hout + a + bias)/3, optional leaky]  (same-thread RMW only)
__global__ __launch_bounds__(256) void gat_agg(
    const int* __restrict__ rowptr, const int* __restrict__ col,
    const unsigned short* __restrict__ z,     // [NN][128] bf16
    const float* __restrict__ el, const float* __restrict__ er,
    float* __restrict__ hout, int mode,
    const float* __restrict__ bL, int act)
{
    int wave = (blockIdx.x * 256 + threadIdx.x) >> 6;
    int lane = threadIdx.x & 63;
    if (wave >= NN) return;
    const int d  = wave;
    const int hp = lane >> 4;
    const int f0 = lane * 2;
    const int p0 = rowptr[d], p1 = rowptr[d + 1];

    const float erh = er[d * HH + hp];
    float ssum = 0.f;
    float ax = 0.f, ay = 0.f;
    for (int e = p0; e < p1; ++e) {
        int s = col[e];
        float v = el[s * HH + hp] + erh;
        v = v > 0.f ? v : 0.2f * v;
        float p = __expf(v);
        ssum += p;
        ushort2 zv = *(const ushort2*)&z[(size_t)s * FH + f0];
        ax += p * bf2f(zv.x);
        ay += p * bf2f(zv.y);
    }
    float inv = (ssum > 0.f) ? 1.f / ssum : 0.f;
    ax *= inv; ay *= inv;

    float2* ap = (float2*)&hout[(size_t)d * FH + f0];
    if (mode == 0) {
        *ap = make_float2(ax, ay);
    } else if (mode == 1) {
        float2 o = *ap;
        o.x += ax; o.y += ay;
        *ap = o;
    } else {
        float2 o = *ap;
        float bx = bL[f0]     + bL[FH + f0]     + bL[2 * FH + f0];
        float by = bL[f0 + 1] + bL[FH + f0 + 1] + bL[2 * FH + f0 + 1];
        float vx = (o.x + ax + bx) * (1.f / 3.f);
        float vy = (o.y + ay + by) * (1.f / 3.f);
        if (act) {
            vx = vx > 0.f ? vx : 0.01f * vx;
            vy = vy > 0.f ? vy : 0.01f * vy;
        }
        *ap = make_float2(vx, vy);
    }
}

extern "C" void kernel_launch(void* const* d_in, const int* in_sizes, int n_in,
                              void* d_out, int out_size, void* d_ws, size_t ws_size,
                              hipStream_t stream)
{
    const float* x    = (const float*)d_in[0];
    const int*   src  = (const int*)d_in[1];
    const int*   dst  = (const int*)d_in[2];
    const float* W0   = (const float*)d_in[3];
    const float* al0  = (const float*)d_in[4];
    const float* ar0  = (const float*)d_in[5];
    const float* b0   = (const float*)d_in[6];
    const float* W12  = (const float*)d_in[7];
    const float* al12 = (const float*)d_in[8];
    const float* ar12 = (const float*)d_in[9];
    const float* b12  = (const float*)d_in[10];
    const float* Wlin = (const float*)d_in[11];
    const float* blin = (const float*)d_in[12];
    float* out = (float*)d_out;

    char* ws = (char*)d_ws;
    size_t off = 0;
    auto alloc = [&](size_t bytes) {
        void* p = ws + off;
        off += (bytes + 255) & ~(size_t)255;
        return p;
    };
    unsigned short* zb = (unsigned short*)alloc((size_t)NN * FH * 2);  // 25.6 MB bf16
    float* hb0  = (float*)alloc((size_t)NN * FH * 4);                  // 51.2 MB
    float* hb1  = (float*)alloc((size_t)NN * FH * 4);                  // 51.2 MB
    float* el   = (float*)alloc((size_t)NN * HH * 4);
    float* er   = (float*)alloc((size_t)NN * HH * 4);
    unsigned short* bt = (unsigned short*)alloc((size_t)10 * 2 * 144 * 128 * 2);
    int* rowptr = (int*)alloc((size_t)(SN + 1) * 4);
    int* cursor = (int*)alloc((size_t)SN * 4);
    int* colarr = (int*)alloc((size_t)RR * EE * 4);
    int* part   = (int*)alloc((size_t)SNB * 4);
    // total ~139 MB — under the proven-safe envelope

    const int g_3n  = (SN + 255) / 256;
    const int g_agg = NN / 4;                    // 25000
    const int g_gm  = (NN + 63) / 64;            // 1563

    // ---- CSR (shared by all layers), XCD-bucketed build ----
    zero_i<<<g_3n, 256, 0, stream>>>(cursor, SN);
    count8<<<8 * NCH, 256, 0, stream>>>(dst, cursor);
    scan_s1<<<SNB, 256, 0, stream>>>(cursor, part);
    scan_s2<<<1, 512, 0, stream>>>(part);
    scan_s3<<<SNB, 256, 0, stream>>>(cursor, part, rowptr);
    copy_i<<<g_3n, 256, 0, stream>>>(rowptr, cursor, SN);
    scatter8<<<8 * NCH, 256, 0, stream>>>(src, dst, cursor, colarr);

    // ---- weight prep ----
    makeB<<<80, 256, 0, stream>>>(W0, al0, ar0, W12, al12, ar12, Wlin, bt);

    // layer l: reads hin (x or previous h), writes hout (ping-pong; never aliased)
    for (int lay = 0; lay < 3; ++lay) {
        const float* bL  = (lay == 0) ? b0 : b12 + (size_t)(lay - 1) * RR * FH;
        const float* hin = (lay == 0) ? x : ((lay == 1) ? hb0 : hb1);
        float* hout      = (lay & 1) ? hb1 : hb0;

        for (int r = 0; r < RR; ++r) {
            const unsigned short* btg = bt + (size_t)(lay * RR + r) * 2 * 144 * 128;
            gemm_f32a<9, true><<<g_gm, 256, 0, stream>>>(
                hin, btg, zb, el, er, nullptr, nullptr, NN);
            int mode = (r == 0) ? 0 : (r == 2 ? 2 : 1);
            gat_agg<<<g_agg, 256, 0, stream>>>(
                rowptr + (size_t)r * NN, colarr, zb, el, er, hout,
                mode, bL, (lay < 2) ? 1 : 0);
        }
    }

    // final linear: [N x 128] @ [128 x 64] + blin   (reads hb0 = layer-2 output)
    gemm_f32a<4, false><<<g_gm, 256, 0, stream>>>(
        hb0, bt + (size_t)9 * 2 * 144 * 128, nullptr, nullptr, nullptr, blin, out, NN);
}

// Round 11
// 995.627 us; speedup vs baseline: 3.1973x; 1.1033x over previous
//
#include <hip/hip_runtime.h>
#include <math.h>

#define NN 100000
#define EE 400000
#define RR 3
#define HH 4
#define DD 32
#define FH 128   // H*D
#define OUTF 64

#define SN (RR * NN)
#define SB 1024
#define SNB ((SN + SB - 1) / SB)  // 293
#define NCH 128                   // edge chunks for bucketed CSR build
#define ECHUNK (RR * EE / NCH)    // 9375
#define RANGE (SN / 8)            // 37500 flattened (r,node) keys per XCD bucket

using bf16x8 = __attribute__((ext_vector_type(8))) short;
using f32x4  = __attribute__((ext_vector_type(4))) float;

#define MFMA16(a, b, c) __builtin_amdgcn_mfma_f32_16x16x32_bf16(a, b, c, 0, 0, 0)

__device__ __forceinline__ unsigned short f2bf(float x) {
    unsigned int u = __float_as_uint(x);
    unsigned int r = (u + 0x7fffu + ((u >> 16) & 1u)) >> 16;
    return (unsigned short)r;
}
__device__ __forceinline__ float bf2f(unsigned short h) {
    return __uint_as_float(((unsigned int)h) << 16);
}

// ---------------- CSR build ----------------

__global__ __launch_bounds__(256) void zero_i(int* __restrict__ p, int n)
{
    int i = blockIdx.x * 256 + threadIdx.x;
    if (i < n) p[i] = 0;
}

// XCD-bucketed degree count: blockIdx&7 = key-range bucket, blockIdx>>3 = edge chunk.
__global__ __launch_bounds__(256) void count8(const int* __restrict__ dst, int* __restrict__ deg)
{
    const int g  = blockIdx.x & 7;
    const int c  = blockIdx.x >> 3;
    const int lo = g * RANGE, hi = lo + RANGE;
    const int e0 = c * ECHUNK, e1 = e0 + ECHUNK;
    for (int i = e0 + threadIdx.x; i < e1; i += 256) {
        int r = (i >= 2 * EE) ? 2 : (i >= EE ? 1 : 0);
        int key = r * NN + dst[i];
        if (key >= lo && key < hi) atomicAdd(&deg[key], 1);
    }
}

__global__ __launch_bounds__(256) void scan_s1(const int* __restrict__ in, int* __restrict__ part)
{
    __shared__ int lds[256];
    int b = blockIdx.x, t = threadIdx.x;
    int base = b * SB + t * 4;
    int s = 0;
    #pragma unroll
    for (int k = 0; k < 4; ++k) { int idx = base + k; if (idx < SN) s += in[idx]; }
    lds[t] = s; __syncthreads();
    for (int off = 128; off > 0; off >>= 1) {
        if (t < off) lds[t] += lds[t + off];
        __syncthreads();
    }
    if (t == 0) part[b] = lds[0];
}

__global__ __launch_bounds__(512) void scan_s2(int* __restrict__ part)
{
    __shared__ int lds[512];
    int t = threadIdx.x;
    lds[t] = (t < SNB) ? part[t] : 0;
    __syncthreads();
    for (int off = 1; off < 512; off <<= 1) {
        int add = (t >= off) ? lds[t - off] : 0;
        __syncthreads();
        lds[t] += add;
        __syncthreads();
    }
    if (t < SNB) part[t] = (t == 0) ? 0 : lds[t - 1];
}

__global__ __launch_bounds__(256) void scan_s3(const int* __restrict__ in, const int* __restrict__ part,
                                               int* __restrict__ out)
{
    __shared__ int lds[256];
    int b = blockIdx.x, t = threadIdx.x;
    int base = b * SB + t * 4;
    int v[4]; int s = 0;
    #pragma unroll
    for (int k = 0; k < 4; ++k) {
        v[k] = (base + k < SN) ? in[base + k] : 0;
        s += v[k];
    }
    lds[t] = s; __syncthreads();
    for (int off = 1; off < 256; off <<= 1) {
        int add = (t >= off) ? lds[t - off] : 0;
        __syncthreads();
        lds[t] += add;
        __syncthreads();
    }
    int run = part[b] + ((t == 0) ? 0 : lds[t - 1]);
    #pragma unroll
    for (int k = 0; k < 4; ++k) {
        if (base + k < SN) out[base + k] = run;
        run += v[k];
    }
    if (b == 0 && t == 0) out[SN] = RR * EE;
}

__global__ __launch_bounds__(256) void copy_i(const int* __restrict__ a, int* __restrict__ b, int n)
{
    int i = blockIdx.x * 256 + threadIdx.x;
    if (i < n) b[i] = a[i];
}

__global__ __launch_bounds__(256) void scatter8(const int* __restrict__ src, const int* __restrict__ dst,
                                                int* __restrict__ cursor, int* __restrict__ col)
{
    const int g  = blockIdx.x & 7;
    const int c  = blockIdx.x >> 3;
    const int lo = g * RANGE, hi = lo + RANGE;
    const int e0 = c * ECHUNK, e1 = e0 + ECHUNK;
    for (int i = e0 + threadIdx.x; i < e1; i += 256) {
        int s = src[i];
        int r = (i >= 2 * EE) ? 2 : (i >= EE ? 1 : 0);
        int key = r * NN + dst[i];
        if (key >= lo && key < hi) {
            int slot = atomicAdd(&cursor[key], 1);
            col[slot] = s;
        }
    }
}

// ---------------- weight prep: BT[g] = split(transpose(augment(W_g))) ----------------
__global__ __launch_bounds__(256) void makeB(
    const float* __restrict__ W0, const float* __restrict__ al0, const float* __restrict__ ar0,
    const float* __restrict__ W12, const float* __restrict__ al12, const float* __restrict__ ar12,
    const float* __restrict__ Wlin, unsigned short* __restrict__ bt)
{
    int g = blockIdx.x >> 3;
    int sub = blockIdx.x & 7;
    const float *W, *al = nullptr, *ar = nullptr;
    if (g < 9) {
        int lay = g / 3, r = g % 3;
        W  = lay ? W12  + (size_t)((lay - 1) * RR + r) * 16384 : W0  + (size_t)r * 16384;
        al = lay ? al12 + (size_t)((lay - 1) * RR + r) * 128   : al0 + (size_t)r * 128;
        ar = lay ? ar12 + (size_t)((lay - 1) * RR + r) * 128   : ar0 + (size_t)r * 128;
    } else {
        W = Wlin;
    }
    unsigned short* hi = bt + (size_t)g * 2 * 144 * 128;
    unsigned short* lo = hi + 144 * 128;
    for (int idx = sub * 256 + threadIdx.x; idx < 144 * 128; idx += 2048) {
        int c = idx >> 7;     // augmented output col 0..143
        int k = idx & 127;
        float v = 0.f;
        if (g < 9) {
            if (c < 128) v = W[k * 128 + c];
            else if (c < 132) {
                int h = c - 128;
                for (int d = 0; d < DD; ++d) v += W[k * 128 + h * DD + d] * al[h * DD + d];
            } else if (c < 136) {
                int h = c - 132;
                for (int d = 0; d < DD; ++d) v += W[k * 128 + h * DD + d] * ar[h * DD + d];
            }
        } else {
            if (c < OUTF) v = W[k * OUTF + c];
        }
        unsigned short h16 = f2bf(v);
        hi[idx] = h16;
        lo[idx] = f2bf(v - bf2f(h16));
    }
}

// ---------------- split-bf16 MFMA GEMM with LDS-staged B ----------------
// C = A @ (B1+B2), A fp32 with in-register hi/lo Markidis split (3 MFMAs/tile).
// BT global: [hi 144x128][lo 144x128] bf16. Staged into 72KB LDS, XOR-swizzled.
// AUG (NT=9): z [M][128] bf16 + el/er [M][4] fp32. OUT (NT=4): outp [M][64] + bias.
template <int NT, bool AUG>
__global__ __launch_bounds__(256) void gemm_f32a(
    const float* __restrict__ A, const unsigned short* __restrict__ BT,
    unsigned short* __restrict__ z, float* __restrict__ el, float* __restrict__ er,
    const float* __restrict__ bias, float* __restrict__ outp, int M)
{
    __shared__ unsigned short Bs[288 * 128];   // 72 KB, rows 0..143 hi, 144..287 lo

    const int lane = threadIdx.x & 63;
    const int wid  = threadIdx.x >> 6;

    // stage BT -> LDS (16B chunks), swizzled
    {
        const uint4* s4 = (const uint4*)BT;    // 4608 chunks of 16B
        for (int i = threadIdx.x; i < 4608; i += 256) {
            int bo  = i << 4;
            int row = bo >> 8;
            int cb  = bo & 255;
            *(uint4*)((char*)Bs + (row << 8) + (cb ^ ((row & 7) << 4))) = s4[i];
        }
    }
    __syncthreads();

    const int row0 = blockIdx.x * 64 + wid * 16;
    const int arow = min(row0 + (lane & 15), M - 1);
    const int koff = (lane >> 4) * 8;

    f32x4 acc[NT];
    #pragma unroll
    for (int j = 0; j < NT; ++j) acc[j] = (f32x4){0.f, 0.f, 0.f, 0.f};

    #pragma unroll
    for (int kk = 0; kk < 4; ++kk) {
        const int ak = kk * 32 + koff;
        const float* ap = A + (size_t)arow * 128 + ak;
        float4 v0 = *(const float4*)ap;
        float4 v1 = *(const float4*)(ap + 4);
        float vv[8] = {v0.x, v0.y, v0.z, v0.w, v1.x, v1.y, v1.z, v1.w};
        bf16x8 a1, a2;
        #pragma unroll
        for (int t = 0; t < 8; ++t) {
            unsigned short h = f2bf(vv[t]);
            a1[t] = (short)h;
            a2[t] = (short)f2bf(vv[t] - bf2f(h));
        }
        const int cb = ak * 2;                 // byte col within 256B row
        #pragma unroll
        for (int j = 0; j < NT; ++j) {
            const int r1 = j * 16 + (lane & 15);
            const int r2 = r1 + 144;           // same (row&7) as r1
            const int sw = cb ^ ((r1 & 7) << 4);
            bf16x8 b1 = *(const bf16x8*)((const char*)Bs + (r1 << 8) + sw);
            bf16x8 b2 = *(const bf16x8*)((const char*)Bs + (r2 << 8) + sw);
            acc[j] = MFMA16(a2, b1, acc[j]);
            acc[j] = MFMA16(a1, b2, acc[j]);
            acc[j] = MFMA16(a1, b1, acc[j]);
        }
    }

    const int crow0 = row0 + ((lane >> 4) << 2);
    const int ccol  = lane & 15;
    #pragma unroll
    for (int q = 0; q < 4; ++q) {
        int row = crow0 + q;
        if (row >= M) continue;
        if (AUG) {
            unsigned short* zr = z + (size_t)row * 128;
            #pragma unroll
            for (int j = 0; j < 8; ++j)
                zr[j * 16 + ccol] = f2bf(acc[j][q]);
            float av = acc[8][q];
            if (ccol < 4)      el[row * 4 + ccol] = av;
            else if (ccol < 8) er[row * 4 + ccol - 4] = av;
        } else {
            #pragma unroll
            for (int j = 0; j < 4; ++j)
                outp[(size_t)row * 64 + j * 16 + ccol] = acc[j][q] + bias[j * 16 + ccol];
        }
    }
}

// ---------------- merged 3-relation softmax + aggregation + finalize ----------------
// One wave per dst node. Loops relations internally, register-accumulates hsum,
// single pure write of h (no RMW chain through memory, no atomics).
__global__ __launch_bounds__(256) void gat_agg3(
    const int* __restrict__ rowptr,            // [SN+1]
    const int* __restrict__ col,
    const unsigned short* __restrict__ z3,     // [3][NN][128] bf16
    const float* __restrict__ el3, const float* __restrict__ er3,  // [3][NN][4]
    float* __restrict__ hout,
    const float* __restrict__ bL, int act)
{
    int wave = (blockIdx.x * 256 + threadIdx.x) >> 6;
    int lane = threadIdx.x & 63;
    if (wave >= NN) return;
    const int d  = wave;
    const int hp = lane >> 4;
    const int f0 = lane * 2;

    float hx = 0.f, hy = 0.f;
    #pragma unroll
    for (int r = 0; r < RR; ++r) {
        const int p0 = rowptr[r * NN + d], p1 = rowptr[r * NN + d + 1];
        const float erh = er3[((size_t)r * NN + d) * 4 + hp];
        const float* elr = el3 + (size_t)r * NN * 4;
        const unsigned short* zr = z3 + (size_t)r * NN * 128;
        float ssum = 0.f;
        float ax = 0.f, ay = 0.f;
        for (int e = p0; e < p1; ++e) {
            int s = col[e];
            float v = elr[s * 4 + hp] + erh;
            v = v > 0.f ? v : 0.2f * v;
            float p = __expf(v);
            ssum += p;
            ushort2 zv = *(const ushort2*)&zr[(size_t)s * FH + f0];
            ax += p * bf2f(zv.x);
            ay += p * bf2f(zv.y);
        }
        float inv = (ssum > 0.f) ? 1.f / ssum : 0.f;
        hx += ax * inv;
        hy += ay * inv;
    }

    float bx = bL[f0]     + bL[FH + f0]     + bL[2 * FH + f0];
    float by = bL[f0 + 1] + bL[FH + f0 + 1] + bL[2 * FH + f0 + 1];
    float vx = (hx + bx) * (1.f / 3.f);
    float vy = (hy + by) * (1.f / 3.f);
    if (act) {
        vx = vx > 0.f ? vx : 0.01f * vx;
        vy = vy > 0.f ? vy : 0.01f * vy;
    }
    *(float2*)&hout[(size_t)d * FH + f0] = make_float2(vx, vy);
}

extern "C" void kernel_launch(void* const* d_in, const int* in_sizes, int n_in,
                              void* d_out, int out_size, void* d_ws, size_t ws_size,
                              hipStream_t stream)
{
    const float* x    = (const float*)d_in[0];
    const int*   src  = (const int*)d_in[1];
    const int*   dst  = (const int*)d_in[2];
    const float* W0   = (const float*)d_in[3];
    const float* al0  = (const float*)d_in[4];
    const float* ar0  = (const float*)d_in[5];
    const float* b0   = (const float*)d_in[6];
    const float* W12  = (const float*)d_in[7];
    const float* al12 = (const float*)d_in[8];
    const float* ar12 = (const float*)d_in[9];
    const float* b12  = (const float*)d_in[10];
    const float* Wlin = (const float*)d_in[11];
    const float* blin = (const float*)d_in[12];
    float* out = (float*)d_out;

    char* ws = (char*)d_ws;
    size_t off = 0;
    auto alloc = [&](size_t bytes) {
        void* p = ws + off;
        off += (bytes + 255) & ~(size_t)255;
        return p;
    };
    unsigned short* zb3 = (unsigned short*)alloc((size_t)RR * NN * FH * 2); // 76.8 MB bf16
    float* hb   = (float*)alloc((size_t)NN * FH * 4);                       // 51.2 MB
    float* el3  = (float*)alloc((size_t)RR * NN * HH * 4);                  // 4.8 MB
    float* er3  = (float*)alloc((size_t)RR * NN * HH * 4);                  // 4.8 MB
    unsigned short* bt = (unsigned short*)alloc((size_t)10 * 2 * 144 * 128 * 2);
    int* rowptr = (int*)alloc((size_t)(SN + 1) * 4);
    int* cursor = (int*)alloc((size_t)SN * 4);
    int* colarr = (int*)alloc((size_t)RR * EE * 4);
    int* part   = (int*)alloc((size_t)SNB * 4);
    // total ~146 MB — under the 165 MB envelope proven by r4/r7/r9

    const int g_3n  = (SN + 255) / 256;
    const int g_agg = NN / 4;                    // 25000
    const int g_gm  = (NN + 63) / 64;            // 1563

    // ---- CSR (shared by all layers), XCD-bucketed build ----
    zero_i<<<g_3n, 256, 0, stream>>>(cursor, SN);
    count8<<<8 * NCH, 256, 0, stream>>>(dst, cursor);
    scan_s1<<<SNB, 256, 0, stream>>>(cursor, part);
    scan_s2<<<1, 512, 0, stream>>>(part);
    scan_s3<<<SNB, 256, 0, stream>>>(cursor, part, rowptr);
    copy_i<<<g_3n, 256, 0, stream>>>(rowptr, cursor, SN);
    scatter8<<<8 * NCH, 256, 0, stream>>>(src, dst, cursor, colarr);

    // ---- weight prep ----
    makeB<<<80, 256, 0, stream>>>(W0, al0, ar0, W12, al12, ar12, Wlin, bt);

    // layer: 3x GEMM (read hin, write zb3[r]/el3[r]/er3[r]) then one agg3
    // (read zb3/el3/er3, pure-write hb). hin==hb for lay>0: agg3 only runs
    // after all 3 GEMMs complete (stream order) -> safe in-place update.
    for (int lay = 0; lay < 3; ++lay) {
        const float* bL  = (lay == 0) ? b0 : b12 + (size_t)(lay - 1) * RR * FH;
        const float* hin = (lay == 0) ? x : hb;

        for (int r = 0; r < RR; ++r) {
            const unsigned short* btg = bt + (size_t)(lay * RR + r) * 2 * 144 * 128;
            gemm_f32a<9, true><<<g_gm, 256, 0, stream>>>(
                hin, btg,
                zb3 + (size_t)r * NN * FH,
                el3 + (size_t)r * NN * HH,
                er3 + (size_t)r * NN * HH,
                nullptr, nullptr, NN);
        }
        gat_agg3<<<g_agg, 256, 0, stream>>>(
            rowptr, colarr, zb3, el3, er3, hb, bL, (lay < 2) ? 1 : 0);
    }

    // final linear: [N x 128] @ [128 x 64] + blin
    gemm_f32a<4, false><<<g_gm, 256, 0, stream>>>(
        hb, bt + (size_t)9 * 2 * 144 * 128, nullptr, nullptr, nullptr, blin, out, NN);
}

// Round 12
// 817.063 us; speedup vs baseline: 3.8961x; 1.2185x over previous
//
#include <hip/hip_runtime.h>
#include <math.h>

#define NN 100000
#define EE 400000
#define RR 3
#define HH 4
#define DD 32
#define FH 128   // H*D
#define OUTF 64

#define SN (RR * NN)
#define SB 1024
#define SNB ((SN + SB - 1) / SB)  // 293
#define NCH 128                   // edge chunks for bucketed CSR build
#define ECHUNK (RR * EE / NCH)    // 9375
#define RANGE (SN / 8)            // 37500 flattened (r,node) keys per XCD bucket

using bf16x8 = __attribute__((ext_vector_type(8))) short;
using f32x4  = __attribute__((ext_vector_type(4))) float;

#define MFMA16(a, b, c) __builtin_amdgcn_mfma_f32_16x16x32_bf16(a, b, c, 0, 0, 0)

__device__ __forceinline__ unsigned short f2bf(float x) {
    unsigned int u = __float_as_uint(x);
    unsigned int r = (u + 0x7fffu + ((u >> 16) & 1u)) >> 16;
    return (unsigned short)r;
}
__device__ __forceinline__ float bf2f(unsigned short h) {
    return __uint_as_float(((unsigned int)h) << 16);
}

// ---------------- CSR build ----------------

__global__ __launch_bounds__(256) void zero_i(int* __restrict__ p, int n)
{
    int i = blockIdx.x * 256 + threadIdx.x;
    if (i < n) p[i] = 0;
}

// XCD-bucketed degree count: blockIdx&7 = key-range bucket, blockIdx>>3 = edge chunk.
__global__ __launch_bounds__(256) void count8(const int* __restrict__ dst, int* __restrict__ deg)
{
    const int g  = blockIdx.x & 7;
    const int c  = blockIdx.x >> 3;
    const int lo = g * RANGE, hi = lo + RANGE;
    const int e0 = c * ECHUNK, e1 = e0 + ECHUNK;
    for (int i = e0 + threadIdx.x; i < e1; i += 256) {
        int r = (i >= 2 * EE) ? 2 : (i >= EE ? 1 : 0);
        int key = r * NN + dst[i];
        if (key >= lo && key < hi) atomicAdd(&deg[key], 1);
    }
}

__global__ __launch_bounds__(256) void scan_s1(const int* __restrict__ in, int* __restrict__ part)
{
    __shared__ int lds[256];
    int b = blockIdx.x, t = threadIdx.x;
    int base = b * SB + t * 4;
    int s = 0;
    #pragma unroll
    for (int k = 0; k < 4; ++k) { int idx = base + k; if (idx < SN) s += in[idx]; }
    lds[t] = s; __syncthreads();
    for (int off = 128; off > 0; off >>= 1) {
        if (t < off) lds[t] += lds[t + off];
        __syncthreads();
    }
    if (t == 0) part[b] = lds[0];
}

__global__ __launch_bounds__(512) void scan_s2(int* __restrict__ part)
{
    __shared__ int lds[512];
    int t = threadIdx.x;
    lds[t] = (t < SNB) ? part[t] : 0;
    __syncthreads();
    for (int off = 1; off < 512; off <<= 1) {
        int add = (t >= off) ? lds[t - off] : 0;
        __syncthreads();
        lds[t] += add;
        __syncthreads();
    }
    if (t < SNB) part[t] = (t == 0) ? 0 : lds[t - 1];
}

__global__ __launch_bounds__(256) void scan_s3(const int* __restrict__ in, const int* __restrict__ part,
                                               int* __restrict__ out)
{
    __shared__ int lds[256];
    int b = blockIdx.x, t = threadIdx.x;
    int base = b * SB + t * 4;
    int v[4]; int s = 0;
    #pragma unroll
    for (int k = 0; k < 4; ++k) {
        v[k] = (base + k < SN) ? in[base + k] : 0;
        s += v[k];
    }
    lds[t] = s; __syncthreads();
    for (int off = 1; off < 256; off <<= 1) {
        int add = (t >= off) ? lds[t - off] : 0;
        __syncthreads();
        lds[t] += add;
        __syncthreads();
    }
    int run = part[b] + ((t == 0) ? 0 : lds[t - 1]);
    #pragma unroll
    for (int k = 0; k < 4; ++k) {
        if (base + k < SN) out[base + k] = run;
        run += v[k];
    }
    if (b == 0 && t == 0) out[SN] = RR * EE;
}

__global__ __launch_bounds__(256) void copy_i(const int* __restrict__ a, int* __restrict__ b, int n)
{
    int i = blockIdx.x * 256 + threadIdx.x;
    if (i < n) b[i] = a[i];
}

__global__ __launch_bounds__(256) void scatter8(const int* __restrict__ src, const int* __restrict__ dst,
                                                int* __restrict__ cursor, int* __restrict__ col)
{
    const int g  = blockIdx.x & 7;
    const int c  = blockIdx.x >> 3;
    const int lo = g * RANGE, hi = lo + RANGE;
    const int e0 = c * ECHUNK, e1 = e0 + ECHUNK;
    for (int i = e0 + threadIdx.x; i < e1; i += 256) {
        int s = src[i];
        int r = (i >= 2 * EE) ? 2 : (i >= EE ? 1 : 0);
        int key = r * NN + dst[i];
        if (key >= lo && key < hi) {
            int slot = atomicAdd(&cursor[key], 1);
            col[slot] = s;
        }
    }
}

// ---------------- weight prep: BT[g] = split(transpose(augment(W_g))) ----------------
__global__ __launch_bounds__(256) void makeB(
    const float* __restrict__ W0, const float* __restrict__ al0, const float* __restrict__ ar0,
    const float* __restrict__ W12, const float* __restrict__ al12, const float* __restrict__ ar12,
    const float* __restrict__ Wlin, unsigned short* __restrict__ bt)
{
    int g = blockIdx.x >> 3;
    int sub = blockIdx.x & 7;
    const float *W, *al = nullptr, *ar = nullptr;
    if (g < 9) {
        int lay = g / 3, r = g % 3;
        W  = lay ? W12  + (size_t)((lay - 1) * RR + r) * 16384 : W0  + (size_t)r * 16384;
        al = lay ? al12 + (size_t)((lay - 1) * RR + r) * 128   : al0 + (size_t)r * 128;
        ar = lay ? ar12 + (size_t)((lay - 1) * RR + r) * 128   : ar0 + (size_t)r * 128;
    } else {
        W = Wlin;
    }
    unsigned short* hi = bt + (size_t)g * 2 * 144 * 128;
    unsigned short* lo = hi + 144 * 128;
    for (int idx = sub * 256 + threadIdx.x; idx < 144 * 128; idx += 2048) {
        int c = idx >> 7;     // augmented output col 0..143
        int k = idx & 127;
        float v = 0.f;
        if (g < 9) {
            if (c < 128) v = W[k * 128 + c];
            else if (c < 132) {
                int h = c - 128;
                for (int d = 0; d < DD; ++d) v += W[k * 128 + h * DD + d] * al[h * DD + d];
            } else if (c < 136) {
                int h = c - 132;
                for (int d = 0; d < DD; ++d) v += W[k * 128 + h * DD + d] * ar[h * DD + d];
            }
        } else {
            if (c < OUTF) v = W[k * OUTF + c];
        }
        unsigned short h16 = f2bf(v);
        hi[idx] = h16;
        lo[idx] = f2bf(v - bf2f(h16));
    }
}

// ---------------- split-bf16 MFMA GEMM with LDS-staged B ----------------
// C = A @ (B1+B2), A fp32 with in-register hi/lo Markidis split (3 MFMAs/tile).
// BT global: [hi 144x128][lo 144x128] bf16. Staged into 72KB LDS, XOR-swizzled.
// AUG (NT=9): z [M][128] bf16 + el/er [M][4] fp32. OUT (NT=4): outp [M][64] + bias.
template <int NT, bool AUG>
__global__ __launch_bounds__(256) void gemm_f32a(
    const float* __restrict__ A, const unsigned short* __restrict__ BT,
    unsigned short* __restrict__ z, float* __restrict__ el, float* __restrict__ er,
    const float* __restrict__ bias, float* __restrict__ outp, int M)
{
    __shared__ unsigned short Bs[288 * 128];   // 72 KB, rows 0..143 hi, 144..287 lo

    const int lane = threadIdx.x & 63;
    const int wid  = threadIdx.x >> 6;

    // stage BT -> LDS (16B chunks), swizzled
    {
        const uint4* s4 = (const uint4*)BT;    // 4608 chunks of 16B
        for (int i = threadIdx.x; i < 4608; i += 256) {
            int bo  = i << 4;
            int row = bo >> 8;
            int cb  = bo & 255;
            *(uint4*)((char*)Bs + (row << 8) + (cb ^ ((row & 7) << 4))) = s4[i];
        }
    }
    __syncthreads();

    const int row0 = blockIdx.x * 64 + wid * 16;
    const int arow = min(row0 + (lane & 15), M - 1);
    const int koff = (lane >> 4) * 8;

    f32x4 acc[NT];
    #pragma unroll
    for (int j = 0; j < NT; ++j) acc[j] = (f32x4){0.f, 0.f, 0.f, 0.f};

    #pragma unroll
    for (int kk = 0; kk < 4; ++kk) {
        const int ak = kk * 32 + koff;
        const float* ap = A + (size_t)arow * 128 + ak;
        float4 v0 = *(const float4*)ap;
        float4 v1 = *(const float4*)(ap + 4);
        float vv[8] = {v0.x, v0.y, v0.z, v0.w, v1.x, v1.y, v1.z, v1.w};
        bf16x8 a1, a2;
        #pragma unroll
        for (int t = 0; t < 8; ++t) {
            unsigned short h = f2bf(vv[t]);
            a1[t] = (short)h;
            a2[t] = (short)f2bf(vv[t] - bf2f(h));
        }
        const int cb = ak * 2;                 // byte col within 256B row
        #pragma unroll
        for (int j = 0; j < NT; ++j) {
            const int r1 = j * 16 + (lane & 15);
            const int r2 = r1 + 144;           // same (row&7) as r1
            const int sw = cb ^ ((r1 & 7) << 4);
            bf16x8 b1 = *(const bf16x8*)((const char*)Bs + (r1 << 8) + sw);
            bf16x8 b2 = *(const bf16x8*)((const char*)Bs + (r2 << 8) + sw);
            acc[j] = MFMA16(a2, b1, acc[j]);
            acc[j] = MFMA16(a1, b2, acc[j]);
            acc[j] = MFMA16(a1, b1, acc[j]);
        }
    }

    const int crow0 = row0 + ((lane >> 4) << 2);
    const int ccol  = lane & 15;
    #pragma unroll
    for (int q = 0; q < 4; ++q) {
        int row = crow0 + q;
        if (row >= M) continue;
        if (AUG) {
            unsigned short* zr = z + (size_t)row * 128;
            #pragma unroll
            for (int j = 0; j < 8; ++j)
                zr[j * 16 + ccol] = f2bf(acc[j][q]);
            float av = acc[8][q];
            if (ccol < 4)      el[row * 4 + ccol] = av;
            else if (ccol < 8) er[row * 4 + ccol - 4] = av;
        } else {
            #pragma unroll
            for (int j = 0; j < 4; ++j)
                outp[(size_t)row * 64 + j * 16 + ccol] = acc[j][q] + bias[j * 16 + ccol];
        }
    }
}

// ---------------- merged 3-relation softmax + aggregation (4 edges in flight) ----------------
// One wave per dst. The 4 16-lane groups each own one edge of a x4 chunk:
// group g loads edge (base+g)'s z row as 16B/lane (4 random 256B rows outstanding).
// Lane li covers features [li*8, li*8+8) (single head since 8|32). Per relation:
// groups accumulate partial {sum p, sum p*z}; psum reduced over groups (2 shfl),
// hsum += acc * (1/psum). Final group-reduction + bias + act + pure 512B write.
__global__ __launch_bounds__(256) void gat_agg3(
    const int* __restrict__ rowptr,            // [SN+1]
    const int* __restrict__ col,
    const unsigned short* __restrict__ z3,     // [3][NN][128] bf16
    const float* __restrict__ el3, const float* __restrict__ er3,  // [3][NN][4]
    float* __restrict__ hout,
    const float* __restrict__ bL, int act)
{
    int wave = (blockIdx.x * 256 + threadIdx.x) >> 6;
    int lane = threadIdx.x & 63;
    if (wave >= NN) return;
    const int d    = wave;
    const int grp  = lane >> 4;        // edge slot 0..3
    const int li   = lane & 15;
    const int head = li >> 2;          // head of this lane's features
    const int fb   = li << 3;          // feature base (8 feats)

    float hsum[8] = {0.f, 0.f, 0.f, 0.f, 0.f, 0.f, 0.f, 0.f};

    #pragma unroll
    for (int r = 0; r < RR; ++r) {
        const int p0 = rowptr[r * NN + d], p1 = rowptr[r * NN + d + 1];
        const float erh = er3[((size_t)r * NN + d) * 4 + head];
        const float* elr = el3 + (size_t)r * NN * 4;
        const unsigned short* zr = z3 + (size_t)r * NN * 128;

        float psum = 0.f;
        float acc[8] = {0.f, 0.f, 0.f, 0.f, 0.f, 0.f, 0.f, 0.f};
        for (int base = p0; base < p1; base += 4) {
            int e = base + grp;
            if (e < p1) {                      // group-uniform predicate
                int s = col[e];
                float v = elr[s * 4 + head] + erh;
                v = v > 0.f ? v : 0.2f * v;
                float p = __expf(v);
                psum += p;
                uint4 zv = *(const uint4*)(zr + (size_t)s * 128 + fb);
                acc[0] += p * bf2f((unsigned short)(zv.x & 0xffffu));
                acc[1] += p * bf2f((unsigned short)(zv.x >> 16));
                acc[2] += p * bf2f((unsigned short)(zv.y & 0xffffu));
                acc[3] += p * bf2f((unsigned short)(zv.y >> 16));
                acc[4] += p * bf2f((unsigned short)(zv.z & 0xffffu));
                acc[5] += p * bf2f((unsigned short)(zv.z >> 16));
                acc[6] += p * bf2f((unsigned short)(zv.w & 0xffffu));
                acc[7] += p * bf2f((unsigned short)(zv.w >> 16));
            }
        }
        // sum p over the 4 groups (per head; lanes of same head hold equal psum)
        psum += __shfl_xor(psum, 16);
        psum += __shfl_xor(psum, 32);
        float inv = (psum > 0.f) ? 1.f / psum : 0.f;
        #pragma unroll
        for (int j = 0; j < 8; ++j) hsum[j] += acc[j] * inv;
    }

    // reduce group partials (features identical across groups)
    #pragma unroll
    for (int j = 0; j < 8; ++j) {
        hsum[j] += __shfl_xor(hsum[j], 16);
        hsum[j] += __shfl_xor(hsum[j], 32);
    }

    if (grp == 0) {
        float o[8];
        #pragma unroll
        for (int j = 0; j < 8; ++j) {
            int f = fb + j;
            float b = bL[f] + bL[FH + f] + bL[2 * FH + f];
            float v = (hsum[j] + b) * (1.f / 3.f);
            if (act) v = v > 0.f ? v : 0.01f * v;
            o[j] = v;
        }
        float4* op = (float4*)&hout[(size_t)d * FH + fb];
        op[0] = make_float4(o[0], o[1], o[2], o[3]);
        op[1] = make_float4(o[4], o[5], o[6], o[7]);
    }
}

extern "C" void kernel_launch(void* const* d_in, const int* in_sizes, int n_in,
                              void* d_out, int out_size, void* d_ws, size_t ws_size,
                              hipStream_t stream)
{
    const float* x    = (const float*)d_in[0];
    const int*   src  = (const int*)d_in[1];
    const int*   dst  = (const int*)d_in[2];
    const float* W0   = (const float*)d_in[3];
    const float* al0  = (const float*)d_in[4];
    const float* ar0  = (const float*)d_in[5];
    const float* b0   = (const float*)d_in[6];
    const float* W12  = (const float*)d_in[7];
    const float* al12 = (const float*)d_in[8];
    const float* ar12 = (const float*)d_in[9];
    const float* b12  = (const float*)d_in[10];
    const float* Wlin = (const float*)d_in[11];
    const float* blin = (const float*)d_in[12];
    float* out = (float*)d_out;

    char* ws = (char*)d_ws;
    size_t off = 0;
    auto alloc = [&](size_t bytes) {
        void* p = ws + off;
        off += (bytes + 255) & ~(size_t)255;
        return p;
    };
    unsigned short* zb3 = (unsigned short*)alloc((size_t)RR * NN * FH * 2); // 76.8 MB bf16
    float* hb   = (float*)alloc((size_t)NN * FH * 4);                       // 51.2 MB
    float* el3  = (float*)alloc((size_t)RR * NN * HH * 4);                  // 4.8 MB
    float* er3  = (float*)alloc((size_t)RR * NN * HH * 4);                  // 4.8 MB
    unsigned short* bt = (unsigned short*)alloc((size_t)10 * 2 * 144 * 128 * 2);
    int* rowptr = (int*)alloc((size_t)(SN + 1) * 4);
    int* cursor = (int*)alloc((size_t)SN * 4);
    int* colarr = (int*)alloc((size_t)RR * EE * 4);
    int* part   = (int*)alloc((size_t)SNB * 4);
    // total ~146 MB — under the 165 MB envelope proven by r4/r7/r9

    const int g_3n  = (SN + 255) / 256;
    const int g_agg = NN / 4;                    // 25000
    const int g_gm  = (NN + 63) / 64;            // 1563

    // ---- CSR (shared by all layers), XCD-bucketed build ----
    zero_i<<<g_3n, 256, 0, stream>>>(cursor, SN);
    count8<<<8 * NCH, 256, 0, stream>>>(dst, cursor);
    scan_s1<<<SNB, 256, 0, stream>>>(cursor, part);
    scan_s2<<<1, 512, 0, stream>>>(part);
    scan_s3<<<SNB, 256, 0, stream>>>(cursor, part, rowptr);
    copy_i<<<g_3n, 256, 0, stream>>>(rowptr, cursor, SN);
    scatter8<<<8 * NCH, 256, 0, stream>>>(src, dst, cursor, colarr);

    // ---- weight prep ----
    makeB<<<80, 256, 0, stream>>>(W0, al0, ar0, W12, al12, ar12, Wlin, bt);

    // layer: 3x GEMM (read hin, write zb3[r]/el3[r]/er3[r]) then one agg3
    // (read zb3/el3/er3, pure-write hb). hin==hb for lay>0: agg3 only runs
    // after all 3 GEMMs complete (stream order) -> safe in-place update.
    for (int lay = 0; lay < 3; ++lay) {
        const float* bL  = (lay == 0) ? b0 : b12 + (size_t)(lay - 1) * RR * FH;
        const float* hin = (lay == 0) ? x : hb;

        for (int r = 0; r < RR; ++r) {
            const unsigned short* btg = bt + (size_t)(lay * RR + r) * 2 * 144 * 128;
            gemm_f32a<9, true><<<g_gm, 256, 0, stream>>>(
                hin, btg,
                zb3 + (size_t)r * NN * FH,
                el3 + (size_t)r * NN * HH,
                er3 + (size_t)r * NN * HH,
                nullptr, nullptr, NN);
        }
        gat_agg3<<<g_agg, 256, 0, stream>>>(
            rowptr, colarr, zb3, el3, er3, hb, bL, (lay < 2) ? 1 : 0);
    }

    // final linear: [N x 128] @ [128 x 64] + blin
    gemm_f32a<4, false><<<g_gm, 256, 0, stream>>>(
        hb, bt + (size_t)9 * 2 * 144 * 128, nullptr, nullptr, nullptr, blin, out, NN);
}